// Round 1
// baseline (454.573 us; speedup 1.0000x reference)
//
#include <hip/hip_runtime.h>
#include <hip/hip_bf16.h>
#include <cstdint>

#define D_DIM 1024
#define S_DIM 2048
#define B_DIM 2
#define NROWS 4096
#define H_DIM 16
#define HD_DIM 64
#define LOG2E 1.4426950408889634f

typedef __bf16 bf16x8 __attribute__((ext_vector_type(8)));
typedef float f32x4 __attribute__((ext_vector_type(4)));

#define MFMA16(a, b, c) __builtin_amdgcn_mfma_f32_16x16x32_bf16(a, b, c, 0, 0, 0)

__device__ __forceinline__ void async_cp16(const void* g, void* lds) {
  __builtin_amdgcn_global_load_lds(
      (const __attribute__((address_space(1))) void*)(uintptr_t)g,
      (__attribute__((address_space(3))) void*)(uint32_t)(uintptr_t)lds, 16, 0, 0);
}

__device__ __forceinline__ unsigned short f2bf(float f) {
  __hip_bfloat16 h = __float2bfloat16(f);
  return __builtin_bit_cast(unsigned short, h);
}

__device__ __forceinline__ float gelu_f(float v) {
  return 0.5f * v * (1.f + tanhf(0.79788456f * (v + 0.044715f * v * v * v)));
}

// ---------------- weight transpose + cast: W[K][N] f32 -> Wt[N][K] bf16 ------
__global__ __launch_bounds__(256) void transpose_cast_kernel(
    const float* __restrict__ W, __hip_bfloat16* __restrict__ Wt, int K, int N) {
  __shared__ float tile[32][33];
  int n0 = blockIdx.x * 32, k0 = blockIdx.y * 32;
  int tx = threadIdx.x, ty = threadIdx.y;
#pragma unroll
  for (int i = 0; i < 32; i += 8)
    tile[ty + i][tx] = W[(size_t)(k0 + ty + i) * N + n0 + tx];
  __syncthreads();
#pragma unroll
  for (int i = 0; i < 32; i += 8)
    Wt[(size_t)(n0 + ty + i) * K + k0 + tx] = __float2bfloat16(tile[tx][ty + i]);
}

// ---------------- layernorm (ddof=1) f32 -> bf16 -----------------------------
__global__ __launch_bounds__(256) void ln_kernel(
    const float* __restrict__ x, const float* __restrict__ sc,
    const float* __restrict__ bi, __hip_bfloat16* __restrict__ out) {
  int row = blockIdx.x, t = threadIdx.x;
  float4 v = ((const float4*)(x + (size_t)row * D_DIM))[t];
  float s = v.x + v.y + v.z + v.w;
  float ss = v.x * v.x + v.y * v.y + v.z * v.z + v.w * v.w;
#pragma unroll
  for (int off = 32; off > 0; off >>= 1) {
    s += __shfl_xor(s, off);
    ss += __shfl_xor(ss, off);
  }
  __shared__ float red[8];
  int wid = t >> 6;
  if ((t & 63) == 0) { red[wid] = s; red[4 + wid] = ss; }
  __syncthreads();
  s = red[0] + red[1] + red[2] + red[3];
  ss = red[4] + red[5] + red[6] + red[7];
  float mean = s * (1.f / 1024.f);
  float var = (ss - 1024.f * mean * mean) * (1.f / 1023.f);
  float inv = rsqrtf(var + 1e-5f);
  float4 scv = ((const float4*)sc)[t];
  float4 biv = ((const float4*)bi)[t];
  ushort4 o;
  o.x = f2bf(scv.x * (v.x - mean) * inv + biv.x);
  o.y = f2bf(scv.y * (v.y - mean) * inv + biv.y);
  o.z = f2bf(scv.z * (v.z - mean) * inv + biv.z);
  o.w = f2bf(scv.w * (v.w - mean) * inv + biv.w);
  ((ushort4*)(out + (size_t)row * D_DIM))[t] = o;
}

// ---------------- GEMM: C[M,N] = A[M,K] @ B, with Bt[N][K] (both bf16) -------
// EPI 0: bf16 out, *oscale.  EPI 1: f32 out + bias + resid.  EPI 2: gelu->bf16 + bias.
template <int EPI>
__global__ __launch_bounds__(256) void gemm_bt_kernel(
    const __hip_bfloat16* __restrict__ A, const __hip_bfloat16* __restrict__ Bt,
    void* __restrict__ Cout, const float* __restrict__ bias,
    const float* __restrict__ resid, int M, int N, int K, float oscale) {
  __shared__ __hip_bfloat16 As[128 * 32];
  __shared__ __hip_bfloat16 Bs[128 * 32];
  const int t = threadIdx.x;
  const int lane = t & 63;
  const int wid = t >> 6;
  const int m0 = blockIdx.x * 128, n0 = blockIdx.y * 128;
  const int wm = (wid >> 1) * 64, wn = (wid & 1) * 64;
  f32x4 acc[4][4] = {};

  const int sr = t >> 2;
  const int sc8 = (t & 3) * 8;
  const __hip_bfloat16* ag = A + (size_t)(m0 + sr) * K + sc8;
  const __hip_bfloat16* bg = Bt + (size_t)(n0 + sr) * K + sc8;

  for (int k0 = 0; k0 < K; k0 += 32) {
    __syncthreads();  // previous compute done before overwriting LDS
    async_cp16(ag + k0, (char*)As + wid * 1024);
    async_cp16(ag + (size_t)64 * K + k0, (char*)As + 4096 + wid * 1024);
    async_cp16(bg + k0, (char*)Bs + wid * 1024);
    async_cp16(bg + (size_t)64 * K + k0, (char*)Bs + 4096 + wid * 1024);
    __syncthreads();  // drains vmcnt -> tiles resident

    bf16x8 af[4], bf[4];
#pragma unroll
    for (int mb = 0; mb < 4; mb++)
      af[mb] = *(const bf16x8*)(As + (wm + mb * 16 + (lane & 15)) * 32 + (lane >> 4) * 8);
#pragma unroll
    for (int nb = 0; nb < 4; nb++)
      bf[nb] = *(const bf16x8*)(Bs + (wn + nb * 16 + (lane & 15)) * 32 + (lane >> 4) * 8);
#pragma unroll
    for (int mb = 0; mb < 4; mb++)
#pragma unroll
      for (int nb = 0; nb < 4; nb++)
        acc[mb][nb] = MFMA16(af[mb], bf[nb], acc[mb][nb]);
  }

  const int rb = m0 + wm + ((lane >> 4) << 2);
  const int cb = n0 + wn + (lane & 15);
#pragma unroll
  for (int mb = 0; mb < 4; mb++) {
#pragma unroll
    for (int nb = 0; nb < 4; nb++) {
      int col = cb + nb * 16;
#pragma unroll
      for (int r = 0; r < 4; r++) {
        int row = rb + mb * 16 + r;
        float v = acc[mb][nb][r];
        if (EPI == 0) {
          ((__hip_bfloat16*)Cout)[(size_t)row * N + col] = __float2bfloat16(v * oscale);
        } else if (EPI == 1) {
          ((float*)Cout)[(size_t)row * N + col] =
              v + bias[col] + resid[(size_t)row * N + col];
        } else {
          ((__hip_bfloat16*)Cout)[(size_t)row * N + col] =
              __float2bfloat16(gelu_f(v + bias[col]));
        }
      }
    }
  }
}

// ---------------- causal flash attention, 1 wave per (bh, 16 q rows) ---------
// Q pre-scaled by 0.125. Layout of q/k/v: [B,S,D] bf16 with head hh at cols hh*64..
__global__ __launch_bounds__(64) void attn_kernel(
    const __hip_bfloat16* __restrict__ Q, const __hip_bfloat16* __restrict__ K,
    const __hip_bfloat16* __restrict__ V, __hip_bfloat16* __restrict__ ctx) {
  __shared__ unsigned short Vs[32 * 64];
  __shared__ unsigned short Ps[32 * 16];
  const int l = threadIdx.x;
  const int ql = l & 15, g = l >> 4;
  const int q0 = blockIdx.x * 16;
  const int bh = blockIdx.y;
  const int b = bh >> 4, hh = bh & 15;
  const size_t headoff = (size_t)b * S_DIM * D_DIM + hh * HD_DIM;
  const __hip_bfloat16* qp = Q + headoff;
  const __hip_bfloat16* kp = K + headoff;
  const __hip_bfloat16* vp = V + headoff;

  const bf16x8 qf0 = *(const bf16x8*)(qp + (size_t)(q0 + ql) * D_DIM + g * 8);
  const bf16x8 qf1 = *(const bf16x8*)(qp + (size_t)(q0 + ql) * D_DIM + 32 + g * 8);

  float m = -3.0e38f, lsum = 0.f;
  f32x4 acc[4] = {};
  const f32x4 z4 = {0.f, 0.f, 0.f, 0.f};

  for (int kv0 = 0; kv0 < q0 + 16; kv0 += 32) {
    // stage V tile [32 kv][64 d] (reg-staged, coalesced 16B loads)
    uint4 vg[4];
#pragma unroll
    for (int i = 0; i < 4; i++)
      vg[i] = *(const uint4*)(vp + (size_t)(kv0 + i * 8 + (l >> 3)) * D_DIM + (l & 7) * 8);
#pragma unroll
    for (int i = 0; i < 4; i++)
      *(uint4*)&Vs[(i * 8 + (l >> 3)) * 64 + (l & 7) * 8] = vg[i];

    // swapped QK^T -> S^T[kv][q]
    bf16x8 ka0 = *(const bf16x8*)(kp + (size_t)(kv0 + ql) * D_DIM + g * 8);
    bf16x8 ka1 = *(const bf16x8*)(kp + (size_t)(kv0 + ql) * D_DIM + 32 + g * 8);
    bf16x8 kb0 = *(const bf16x8*)(kp + (size_t)(kv0 + 16 + ql) * D_DIM + g * 8);
    bf16x8 kb1 = *(const bf16x8*)(kp + (size_t)(kv0 + 16 + ql) * D_DIM + 32 + g * 8);
    f32x4 st0 = MFMA16(ka1, qf1, MFMA16(ka0, qf0, z4));
    f32x4 st1 = MFMA16(kb1, qf1, MFMA16(kb0, qf0, z4));

    // causal mask + tile row-max (row = q = lane&15; kv spread over regs+groups)
    float tmax = -3.0e38f;
#pragma unroll
    for (int r = 0; r < 4; r++) {
      if (kv0 + 4 * g + r > q0 + ql) st0[r] = -3.0e38f;
      if (kv0 + 16 + 4 * g + r > q0 + ql) st1[r] = -3.0e38f;
      tmax = fmaxf(tmax, fmaxf(st0[r], st1[r]));
    }
    tmax = fmaxf(tmax, __shfl_xor(tmax, 16));
    tmax = fmaxf(tmax, __shfl_xor(tmax, 32));
    const float mnew = fmaxf(m, tmax);
    const float alpha = exp2f((m - mnew) * LOG2E);
    float p0[4], p1[4], psum = 0.f;
#pragma unroll
    for (int r = 0; r < 4; r++) {
      p0[r] = exp2f((st0[r] - mnew) * LOG2E);
      p1[r] = exp2f((st1[r] - mnew) * LOG2E);
      psum += p0[r] + p1[r];
    }
    psum += __shfl_xor(psum, 16);
    psum += __shfl_xor(psum, 32);
    lsum = lsum * alpha + psum;
    m = mnew;
#pragma unroll
    for (int d = 0; d < 4; d++) acc[d] *= alpha;

    // P^T -> LDS (bf16)
#pragma unroll
    for (int r = 0; r < 4; r++) {
      Ps[(4 * g + r) * 16 + ql] = f2bf(p0[r]);
      Ps[(16 + 4 * g + r) * 16 + ql] = f2bf(p1[r]);
    }

    // PV: ctx^T[d][q] += V^T[d][kv] @ P^T[kv][q]
    union { unsigned short u[8]; bf16x8 v; } pb, va;
#pragma unroll
    for (int j = 0; j < 8; j++) pb.u[j] = Ps[(g * 8 + j) * 16 + ql];
#pragma unroll
    for (int db = 0; db < 4; db++) {
#pragma unroll
      for (int j = 0; j < 8; j++) va.u[j] = Vs[(g * 8 + j) * 64 + db * 16 + ql];
      acc[db] = MFMA16(va.v, pb.v, acc[db]);
    }
  }

  const float inv = 1.f / lsum;
#pragma unroll
  for (int db = 0; db < 4; db++)
#pragma unroll
    for (int r = 0; r < 4; r++)
      ctx[(size_t)(b * S_DIM + q0 + ql) * D_DIM + hh * HD_DIM + db * 16 + 4 * g + r] =
          __float2bfloat16(acc[db][r] * inv);
}

// ---------------- orchestration ----------------------------------------------
extern "C" void kernel_launch(void* const* d_in, const int* in_sizes, int n_in,
                              void* d_out, int out_size, void* d_ws, size_t ws_size,
                              hipStream_t stream) {
  const float* x = (const float*)d_in[0];
  const float* Wq = (const float*)d_in[1];
  const float* Wk = (const float*)d_in[2];
  const float* Wv = (const float*)d_in[3];
  const float* Wo = (const float*)d_in[4];
  const float* bo = (const float*)d_in[5];
  const float* W1 = (const float*)d_in[6];
  const float* b1 = (const float*)d_in[7];
  const float* W2 = (const float*)d_in[8];
  const float* b2 = (const float*)d_in[9];
  const float* ln1s = (const float*)d_in[10];
  const float* ln1b = (const float*)d_in[11];
  const float* ln2s = (const float*)d_in[12];
  const float* ln2b = (const float*)d_in[13];
  float* out = (float*)d_out;

  char* p = (char*)d_ws;
  auto take = [&](size_t n) { char* r = p; p += (n + 255) & ~(size_t)255; return r; };
  __hip_bfloat16* Wqt = (__hip_bfloat16*)take((size_t)1024 * 1024 * 2);
  __hip_bfloat16* Wkt = (__hip_bfloat16*)take((size_t)1024 * 1024 * 2);
  __hip_bfloat16* Wvt = (__hip_bfloat16*)take((size_t)1024 * 1024 * 2);
  __hip_bfloat16* Wot = (__hip_bfloat16*)take((size_t)1024 * 1024 * 2);
  __hip_bfloat16* W1t = (__hip_bfloat16*)take((size_t)4096 * 1024 * 2);
  __hip_bfloat16* W2t = (__hip_bfloat16*)take((size_t)4096 * 1024 * 2);
  __hip_bfloat16* hbuf = (__hip_bfloat16*)take((size_t)NROWS * 1024 * 2);
  __hip_bfloat16* qbuf = (__hip_bfloat16*)take((size_t)NROWS * 1024 * 2);
  __hip_bfloat16* kbuf = (__hip_bfloat16*)take((size_t)NROWS * 1024 * 2);
  __hip_bfloat16* vbuf = (__hip_bfloat16*)take((size_t)NROWS * 1024 * 2);
  __hip_bfloat16* ctxbuf = (__hip_bfloat16*)take((size_t)NROWS * 1024 * 2);
  float* x1buf = (float*)take((size_t)NROWS * 1024 * 4);
  __hip_bfloat16* h2buf = (__hip_bfloat16*)take((size_t)NROWS * 1024 * 2);
  __hip_bfloat16* gbuf = (__hip_bfloat16*)take((size_t)NROWS * 4096 * 2);

  dim3 tb(32, 8);
  transpose_cast_kernel<<<dim3(32, 32), tb, 0, stream>>>(Wq, Wqt, 1024, 1024);
  transpose_cast_kernel<<<dim3(32, 32), tb, 0, stream>>>(Wk, Wkt, 1024, 1024);
  transpose_cast_kernel<<<dim3(32, 32), tb, 0, stream>>>(Wv, Wvt, 1024, 1024);
  transpose_cast_kernel<<<dim3(32, 32), tb, 0, stream>>>(Wo, Wot, 1024, 1024);
  transpose_cast_kernel<<<dim3(128, 32), tb, 0, stream>>>(W1, W1t, 1024, 4096);
  transpose_cast_kernel<<<dim3(32, 128), tb, 0, stream>>>(W2, W2t, 4096, 1024);

  ln_kernel<<<NROWS, 256, 0, stream>>>(x, ln1s, ln1b, hbuf);

  gemm_bt_kernel<0><<<dim3(32, 8), 256, 0, stream>>>(hbuf, Wqt, qbuf, nullptr, nullptr,
                                                     NROWS, 1024, 1024, 0.125f);
  gemm_bt_kernel<0><<<dim3(32, 8), 256, 0, stream>>>(hbuf, Wkt, kbuf, nullptr, nullptr,
                                                     NROWS, 1024, 1024, 1.f);
  gemm_bt_kernel<0><<<dim3(32, 8), 256, 0, stream>>>(hbuf, Wvt, vbuf, nullptr, nullptr,
                                                     NROWS, 1024, 1024, 1.f);

  attn_kernel<<<dim3(S_DIM / 16, B_DIM * H_DIM), 64, 0, stream>>>(qbuf, kbuf, vbuf, ctxbuf);

  gemm_bt_kernel<1><<<dim3(32, 8), 256, 0, stream>>>(ctxbuf, Wot, x1buf, bo, x,
                                                     NROWS, 1024, 1024, 1.f);

  ln_kernel<<<NROWS, 256, 0, stream>>>(x1buf, ln2s, ln2b, h2buf);

  gemm_bt_kernel<2><<<dim3(32, 32), 256, 0, stream>>>(h2buf, W1t, gbuf, b1, nullptr,
                                                      NROWS, 4096, 1024, 1.f);

  gemm_bt_kernel<1><<<dim3(32, 8), 256, 0, stream>>>(gbuf, W2t, out, b2, x1buf,
                                                     NROWS, 1024, 4096, 1.f);
}

// Round 2
// 311.034 us; speedup vs baseline: 1.4615x; 1.4615x over previous
//
#include <hip/hip_runtime.h>
#include <hip/hip_bf16.h>
#include <cstdint>

#define D_DIM 1024
#define S_DIM 2048
#define B_DIM 2
#define NROWS 4096
#define H_DIM 16
#define LOG2E 1.4426950408889634f
#define QSCALE (0.125f * LOG2E)

typedef __bf16 bf16x8 __attribute__((ext_vector_type(8)));
typedef float f32x4 __attribute__((ext_vector_type(4)));

#define MFMA16(a, b, c) __builtin_amdgcn_mfma_f32_16x16x32_bf16(a, b, c, 0, 0, 0)

__device__ __forceinline__ void async_cp16(const void* g, void* lds) {
  __builtin_amdgcn_global_load_lds(
      (const __attribute__((address_space(1))) void*)(uintptr_t)g,
      (__attribute__((address_space(3))) void*)(uint32_t)(uintptr_t)lds, 16, 0, 0);
}

__device__ __forceinline__ unsigned short f2bf(float f) {
  __hip_bfloat16 h = __float2bfloat16(f);
  return __builtin_bit_cast(unsigned short, h);
}

__device__ __forceinline__ float gelu_f(float v) {
  return 0.5f * v * (1.f + tanhf(0.79788456f * (v + 0.044715f * v * v * v)));
}

// ---------------- fused weight transpose+cast: 6 matrices in one launch -----
struct TcArgs {
  const float* src[6];
  __hip_bfloat16* dst[6];
  int K[6];
  int N[6];
  int start[6];
};

__global__ __launch_bounds__(256) void transpose_cast6_kernel(TcArgs a) {
  __shared__ float tile[32][33];
  int bid = blockIdx.x, mi = 0;
#pragma unroll
  for (int i = 1; i < 6; i++)
    if (bid >= a.start[i]) mi = i;
  const float* W = a.src[mi];
  __hip_bfloat16* Wt = a.dst[mi];
  int K = a.K[mi], N = a.N[mi];
  int rel = bid - a.start[mi];
  int tilesx = N >> 5;
  int shift = (N == 4096) ? 7 : 5;
  int n0 = (rel & (tilesx - 1)) * 32, k0 = (rel >> shift) * 32;
  int tx = threadIdx.x, ty = threadIdx.y;
#pragma unroll
  for (int i = 0; i < 32; i += 8)
    tile[ty + i][tx] = W[(size_t)(k0 + ty + i) * N + n0 + tx];
  __syncthreads();
#pragma unroll
  for (int i = 0; i < 32; i += 8)
    Wt[(size_t)(n0 + ty + i) * K + k0 + tx] = __float2bfloat16(tile[tx][ty + i]);
}

// ---------------- layernorm (ddof=1) f32 -> bf16 -----------------------------
__global__ __launch_bounds__(256) void ln_kernel(
    const float* __restrict__ x, const float* __restrict__ sc,
    const float* __restrict__ bi, __hip_bfloat16* __restrict__ out) {
  int row = blockIdx.x, t = threadIdx.x;
  float4 v = ((const float4*)(x + (size_t)row * D_DIM))[t];
  float s = v.x + v.y + v.z + v.w;
  float ss = v.x * v.x + v.y * v.y + v.z * v.z + v.w * v.w;
#pragma unroll
  for (int off = 32; off > 0; off >>= 1) {
    s += __shfl_xor(s, off);
    ss += __shfl_xor(ss, off);
  }
  __shared__ float red[8];
  int wid = t >> 6;
  if ((t & 63) == 0) { red[wid] = s; red[4 + wid] = ss; }
  __syncthreads();
  s = red[0] + red[1] + red[2] + red[3];
  ss = red[4] + red[5] + red[6] + red[7];
  float mean = s * (1.f / 1024.f);
  float var = (ss - 1024.f * mean * mean) * (1.f / 1023.f);
  float inv = rsqrtf(var + 1e-5f);
  float4 scv = ((const float4*)sc)[t];
  float4 biv = ((const float4*)bi)[t];
  ushort4 o;
  o.x = f2bf(scv.x * (v.x - mean) * inv + biv.x);
  o.y = f2bf(scv.y * (v.y - mean) * inv + biv.y);
  o.z = f2bf(scv.z * (v.z - mean) * inv + biv.z);
  o.w = f2bf(scv.w * (v.w - mean) * inv + biv.w);
  ((ushort4*)(out + (size_t)row * D_DIM))[t] = o;
}

// ---------------- GEMM: C[M,N] = A[M,K] @ B, with Bt[N][K] (both bf16) -------
// EPI 1: f32 out + bias + resid.  EPI 2: gelu->bf16 + bias.
template <int BN, int EPI>
__global__ __launch_bounds__(256) void gemm_bt_kernel(
    const __hip_bfloat16* __restrict__ A, const __hip_bfloat16* __restrict__ Bt,
    void* __restrict__ Cout, const float* __restrict__ bias,
    const float* __restrict__ resid, int M, int N, int K) {
  constexpr int NBF = BN / 32;
  __shared__ __hip_bfloat16 As[128 * 32];
  __shared__ __hip_bfloat16 Bs[BN * 32];
  const int t = threadIdx.x;
  const int lane = t & 63, wid = t >> 6;
  const int ql = lane & 15, g = lane >> 4;
  const int m0 = blockIdx.x * 128, n0 = blockIdx.y * BN;
  const int wm = (wid >> 1) * 64, wn = (wid & 1) * (BN / 2);
  f32x4 acc[4][NBF] = {};
  const int sr = t >> 2, sc8 = (t & 3) * 8;
  const __hip_bfloat16* ag = A + (size_t)(m0 + sr) * K + sc8;
  const __hip_bfloat16* bg = Bt + (size_t)(n0 + sr) * K + sc8;

  for (int k0 = 0; k0 < K; k0 += 32) {
    __syncthreads();
    async_cp16(ag + k0, (char*)As + wid * 1024);
    async_cp16(ag + (size_t)64 * K + k0, (char*)As + 4096 + wid * 1024);
    async_cp16(bg + k0, (char*)Bs + wid * 1024);
    if constexpr (BN == 128)
      async_cp16(bg + (size_t)64 * K + k0, (char*)Bs + 4096 + wid * 1024);
    __syncthreads();

    bf16x8 af[4], bfr[NBF];
#pragma unroll
    for (int mb = 0; mb < 4; mb++)
      af[mb] = *(const bf16x8*)(As + (wm + mb * 16 + ql) * 32 + g * 8);
#pragma unroll
    for (int nb = 0; nb < NBF; nb++)
      bfr[nb] = *(const bf16x8*)(Bs + (wn + nb * 16 + ql) * 32 + g * 8);
#pragma unroll
    for (int mb = 0; mb < 4; mb++)
#pragma unroll
      for (int nb = 0; nb < NBF; nb++)
        acc[mb][nb] = MFMA16(af[mb], bfr[nb], acc[mb][nb]);
  }

  const int rb = m0 + wm + (g << 2);
  const int cb = n0 + wn + ql;
#pragma unroll
  for (int mb = 0; mb < 4; mb++) {
#pragma unroll
    for (int nb = 0; nb < NBF; nb++) {
      int col = cb + nb * 16;
#pragma unroll
      for (int r = 0; r < 4; r++) {
        int row = rb + mb * 16 + r;
        float v = acc[mb][nb][r];
        if (EPI == 1) {
          ((float*)Cout)[(size_t)row * N + col] =
              v + bias[col] + resid[(size_t)row * N + col];
        } else {
          ((__hip_bfloat16*)Cout)[(size_t)row * N + col] =
              __float2bfloat16(gelu_f(v + bias[col]));
        }
      }
    }
  }
}

// ---------------- fused QKV GEMM: A[4096,1024] x {Wq,Wk,Wv}^T ----------------
// seg 0: Q *= 0.125*log2e -> qb.  seg 1: K -> kb.  seg 2: V transposed -> vt[b,h,d,s].
__global__ __launch_bounds__(256) void qkv_kernel(
    const __hip_bfloat16* __restrict__ A, const __hip_bfloat16* __restrict__ Wqt,
    const __hip_bfloat16* __restrict__ Wkt, const __hip_bfloat16* __restrict__ Wvt,
    __hip_bfloat16* __restrict__ qb, __hip_bfloat16* __restrict__ kb,
    unsigned short* __restrict__ vt) {
  __shared__ __hip_bfloat16 As[128 * 32];
  __shared__ __hip_bfloat16 Bs[128 * 32];
  const int t = threadIdx.x;
  const int lane = t & 63, wid = t >> 6;
  const int ql = lane & 15, g = lane >> 4;
  const int seg = blockIdx.y >> 3;
  const int n0 = (blockIdx.y & 7) * 128;
  const __hip_bfloat16* Bt = seg == 0 ? Wqt : (seg == 1 ? Wkt : Wvt);
  const int m0 = blockIdx.x * 128;
  const int wm = (wid >> 1) * 64, wn = (wid & 1) * 64;
  f32x4 acc[4][4] = {};
  const int sr = t >> 2, sc8 = (t & 3) * 8;
  const __hip_bfloat16* ag = A + (size_t)(m0 + sr) * 1024 + sc8;
  const __hip_bfloat16* bg = Bt + (size_t)(n0 + sr) * 1024 + sc8;

  for (int k0 = 0; k0 < 1024; k0 += 32) {
    __syncthreads();
    async_cp16(ag + k0, (char*)As + wid * 1024);
    async_cp16(ag + (size_t)64 * 1024 + k0, (char*)As + 4096 + wid * 1024);
    async_cp16(bg + k0, (char*)Bs + wid * 1024);
    async_cp16(bg + (size_t)64 * 1024 + k0, (char*)Bs + 4096 + wid * 1024);
    __syncthreads();

    bf16x8 af[4], bfr[4];
#pragma unroll
    for (int mb = 0; mb < 4; mb++)
      af[mb] = *(const bf16x8*)(As + (wm + mb * 16 + ql) * 32 + g * 8);
#pragma unroll
    for (int nb = 0; nb < 4; nb++)
      bfr[nb] = *(const bf16x8*)(Bs + (wn + nb * 16 + ql) * 32 + g * 8);
#pragma unroll
    for (int mb = 0; mb < 4; mb++)
#pragma unroll
      for (int nb = 0; nb < 4; nb++)
        acc[mb][nb] = MFMA16(af[mb], bfr[nb], acc[mb][nb]);
  }

  const int rb = m0 + wm + (g << 2);
  if (seg < 2) {
    __hip_bfloat16* Ob = seg == 0 ? qb : kb;
    const float sc = seg == 0 ? QSCALE : 1.f;
#pragma unroll
    for (int mb = 0; mb < 4; mb++)
#pragma unroll
      for (int nb = 0; nb < 4; nb++) {
        int col = n0 + wn + nb * 16 + ql;
#pragma unroll
        for (int r = 0; r < 4; r++)
          Ob[(size_t)(rb + mb * 16 + r) * 1024 + col] =
              __float2bfloat16(acc[mb][nb][r] * sc);
      }
  } else {
#pragma unroll
    for (int mb = 0; mb < 4; mb++)
#pragma unroll
      for (int nb = 0; nb < 4; nb++) {
        int col = n0 + wn + nb * 16 + ql;
        int h = col >> 6, dh = col & 63;
        int row0 = rb + mb * 16;
        int bb = row0 >> 11, s0 = row0 & 2047;
        ushort4 pk;
        pk.x = f2bf(acc[mb][nb][0]);
        pk.y = f2bf(acc[mb][nb][1]);
        pk.z = f2bf(acc[mb][nb][2]);
        pk.w = f2bf(acc[mb][nb][3]);
        *(ushort4*)(vt + (((size_t)(bb * 16 + h) * 64 + dh) << 11) + s0) = pk;
      }
  }
}

// ---------------- causal flash attention: 1 wave per 32 q-rows ---------------
// Q pre-scaled by 0.125*log2e (exp2-space). K row-major [b,s,h*64+d]; V pre-
// transposed vt[b,h,d,s]. P via per-wave LDS, XOR-swizzled b64 writes/b128 reads.
__global__ __launch_bounds__(256) void attn_kernel(
    const __hip_bfloat16* __restrict__ Q, const __hip_bfloat16* __restrict__ Kb,
    const __hip_bfloat16* __restrict__ Vt, __hip_bfloat16* __restrict__ ctx) {
  __shared__ alignas(16) unsigned short Ps[4][32 * 32];
  const int t = threadIdx.x;
  const int lane = t & 63, wid = t >> 6;
  const int ql = lane & 15, g = lane >> 4;
  const int wg = ((blockIdx.x & 7) << 6) | (blockIdx.x >> 3);  // XCD swizzle
  const int bh = wg >> 4, qig = wg & 15;
  const int qi = wid * 16 + qig;  // balance work across waves of a block
  const int q0 = qi * 32;
  const int b = bh >> 4, hh = bh & 15;
  const __hip_bfloat16* qp = Q + (size_t)b * S_DIM * D_DIM + hh * 64;
  const __hip_bfloat16* kp = Kb + (size_t)b * S_DIM * D_DIM + hh * 64;
  const __hip_bfloat16* vp = Vt + (size_t)bh * 64 * S_DIM;
  unsigned short* Pw = Ps[wid];
  const int sw = (ql & 3) << 4;

  bf16x8 qf[2][2];
#pragma unroll
  for (int qs = 0; qs < 2; qs++)
#pragma unroll
    for (int hf = 0; hf < 2; hf++)
      qf[qs][hf] = *(const bf16x8*)(qp + (size_t)(q0 + qs * 16 + ql) * D_DIM + hf * 32 + g * 8);

  float m[2] = {-3.0e38f, -3.0e38f}, lsum[2] = {0.f, 0.f};
  f32x4 acc[4][2] = {};
  const f32x4 z4 = {0.f, 0.f, 0.f, 0.f};
  const int kvend = q0 + 32;

  bf16x8 ka[2][2];
#pragma unroll
  for (int ks = 0; ks < 2; ks++)
#pragma unroll
    for (int hf = 0; hf < 2; hf++)
      ka[ks][hf] = *(const bf16x8*)(kp + (size_t)(ks * 16 + ql) * D_DIM + hf * 32 + g * 8);

  for (int kv0 = 0; kv0 < kvend; kv0 += 32) {
    bf16x8 va[4];
#pragma unroll
    for (int db = 0; db < 4; db++)
      va[db] = *(const bf16x8*)(vp + (size_t)(db * 16 + ql) * S_DIM + kv0 + 8 * g);

    const int kvn = (kv0 + 32 < kvend) ? kv0 + 32 : kv0;
    bf16x8 kn[2][2];
#pragma unroll
    for (int ks = 0; ks < 2; ks++)
#pragma unroll
      for (int hf = 0; hf < 2; hf++)
        kn[ks][hf] = *(const bf16x8*)(kp + (size_t)(kvn + ks * 16 + ql) * D_DIM + hf * 32 + g * 8);

    f32x4 st[2][2];
#pragma unroll
    for (int ks = 0; ks < 2; ks++)
#pragma unroll
      for (int qs = 0; qs < 2; qs++)
        st[ks][qs] = MFMA16(ka[ks][1], qf[qs][1], MFMA16(ka[ks][0], qf[qs][0], z4));

    if (kv0 + 31 > q0) {  // only the diagonal tile needs masking
#pragma unroll
      for (int ks = 0; ks < 2; ks++)
#pragma unroll
        for (int qs = 0; qs < 2; qs++)
#pragma unroll
          for (int r = 0; r < 4; r++)
            if (kv0 + ks * 16 + 4 * g + r > q0 + qs * 16 + ql) st[ks][qs][r] = -3.0e38f;
    }

#pragma unroll
    for (int qs = 0; qs < 2; qs++) {
      float tm = -3.0e38f;
#pragma unroll
      for (int r = 0; r < 4; r++) tm = fmaxf(tm, fmaxf(st[0][qs][r], st[1][qs][r]));
      tm = fmaxf(tm, __shfl_xor(tm, 16));
      tm = fmaxf(tm, __shfl_xor(tm, 32));
      const float mn = fmaxf(m[qs], tm);
      const float alpha = exp2f(m[qs] - mn);
      float p0[4], p1[4], ps = 0.f;
#pragma unroll
      for (int r = 0; r < 4; r++) {
        p0[r] = exp2f(st[0][qs][r] - mn);
        p1[r] = exp2f(st[1][qs][r] - mn);
        ps += p0[r] + p1[r];
      }
      ps += __shfl_xor(ps, 16);
      ps += __shfl_xor(ps, 32);
      lsum[qs] = lsum[qs] * alpha + ps;
      m[qs] = mn;
#pragma unroll
      for (int db = 0; db < 4; db++) acc[db][qs] *= alpha;
      const int q = qs * 16 + ql;
      ushort4 pk0, pk1;
      pk0.x = f2bf(p0[0]); pk0.y = f2bf(p0[1]); pk0.z = f2bf(p0[2]); pk0.w = f2bf(p0[3]);
      pk1.x = f2bf(p1[0]); pk1.y = f2bf(p1[1]); pk1.z = f2bf(p1[2]); pk1.w = f2bf(p1[3]);
      *(ushort4*)((char*)Pw + q * 64 + ((8 * g) ^ sw)) = pk0;
      *(ushort4*)((char*)Pw + q * 64 + ((32 + 8 * g) ^ sw)) = pk1;
    }

    bf16x8 pb[2];
#pragma unroll
    for (int qs = 0; qs < 2; qs++)
      pb[qs] = *(const bf16x8*)((const char*)Pw + (qs * 16 + ql) * 64 + ((16 * g) ^ sw));
#pragma unroll
    for (int db = 0; db < 4; db++)
#pragma unroll
      for (int qs = 0; qs < 2; qs++)
        acc[db][qs] = MFMA16(va[db], pb[qs], acc[db][qs]);
#pragma unroll
    for (int ks = 0; ks < 2; ks++)
#pragma unroll
      for (int hf = 0; hf < 2; hf++)
        ka[ks][hf] = kn[ks][hf];
  }

#pragma unroll
  for (int qs = 0; qs < 2; qs++) {
    const float inv = 1.f / lsum[qs];
    const int q = q0 + qs * 16 + ql;
    unsigned short* cp = (unsigned short*)ctx + (size_t)(b * S_DIM + q) * D_DIM + hh * 64;
#pragma unroll
    for (int db = 0; db < 4; db++)
#pragma unroll
      for (int i = 0; i < 2; i++) {
        unsigned int lo = f2bf(acc[db][qs][2 * i] * inv);
        unsigned int hi = f2bf(acc[db][qs][2 * i + 1] * inv);
        *(unsigned int*)(cp + db * 16 + 4 * g + 2 * i) = lo | (hi << 16);
      }
  }
}

// ---------------- orchestration ----------------------------------------------
extern "C" void kernel_launch(void* const* d_in, const int* in_sizes, int n_in,
                              void* d_out, int out_size, void* d_ws, size_t ws_size,
                              hipStream_t stream) {
  const float* x = (const float*)d_in[0];
  const float* Wq = (const float*)d_in[1];
  const float* Wk = (const float*)d_in[2];
  const float* Wv = (const float*)d_in[3];
  const float* Wo = (const float*)d_in[4];
  const float* bo = (const float*)d_in[5];
  const float* W1 = (const float*)d_in[6];
  const float* b1 = (const float*)d_in[7];
  const float* W2 = (const float*)d_in[8];
  const float* b2 = (const float*)d_in[9];
  const float* ln1s = (const float*)d_in[10];
  const float* ln1b = (const float*)d_in[11];
  const float* ln2s = (const float*)d_in[12];
  const float* ln2b = (const float*)d_in[13];
  float* out = (float*)d_out;

  char* p = (char*)d_ws;
  auto take = [&](size_t n) { char* r = p; p += (n + 255) & ~(size_t)255; return r; };
  __hip_bfloat16* Wqt = (__hip_bfloat16*)take((size_t)1024 * 1024 * 2);
  __hip_bfloat16* Wkt = (__hip_bfloat16*)take((size_t)1024 * 1024 * 2);
  __hip_bfloat16* Wvt = (__hip_bfloat16*)take((size_t)1024 * 1024 * 2);
  __hip_bfloat16* Wot = (__hip_bfloat16*)take((size_t)1024 * 1024 * 2);
  __hip_bfloat16* W1t = (__hip_bfloat16*)take((size_t)4096 * 1024 * 2);
  __hip_bfloat16* W2t = (__hip_bfloat16*)take((size_t)4096 * 1024 * 2);
  __hip_bfloat16* hbuf = (__hip_bfloat16*)take((size_t)NROWS * 1024 * 2);
  __hip_bfloat16* qbuf = (__hip_bfloat16*)take((size_t)NROWS * 1024 * 2);
  __hip_bfloat16* kbuf = (__hip_bfloat16*)take((size_t)NROWS * 1024 * 2);
  __hip_bfloat16* vtbuf = (__hip_bfloat16*)take((size_t)NROWS * 1024 * 2);
  __hip_bfloat16* ctxbuf = (__hip_bfloat16*)take((size_t)NROWS * 1024 * 2);
  float* x1buf = (float*)take((size_t)NROWS * 1024 * 4);
  __hip_bfloat16* h2buf = (__hip_bfloat16*)take((size_t)NROWS * 1024 * 2);
  __hip_bfloat16* gbuf = (__hip_bfloat16*)take((size_t)NROWS * 4096 * 2);

  TcArgs ta;
  ta.src[0] = Wq;  ta.dst[0] = Wqt;  ta.K[0] = 1024; ta.N[0] = 1024; ta.start[0] = 0;
  ta.src[1] = Wk;  ta.dst[1] = Wkt;  ta.K[1] = 1024; ta.N[1] = 1024; ta.start[1] = 1024;
  ta.src[2] = Wv;  ta.dst[2] = Wvt;  ta.K[2] = 1024; ta.N[2] = 1024; ta.start[2] = 2048;
  ta.src[3] = Wo;  ta.dst[3] = Wot;  ta.K[3] = 1024; ta.N[3] = 1024; ta.start[3] = 3072;
  ta.src[4] = W1;  ta.dst[4] = W1t;  ta.K[4] = 1024; ta.N[4] = 4096; ta.start[4] = 4096;
  ta.src[5] = W2;  ta.dst[5] = W2t;  ta.K[5] = 4096; ta.N[5] = 1024; ta.start[5] = 8192;
  transpose_cast6_kernel<<<12288, dim3(32, 8), 0, stream>>>(ta);

  ln_kernel<<<NROWS, 256, 0, stream>>>(x, ln1s, ln1b, hbuf);

  qkv_kernel<<<dim3(32, 24), 256, 0, stream>>>(hbuf, Wqt, Wkt, Wvt, qbuf, kbuf,
                                               (unsigned short*)vtbuf);

  attn_kernel<<<512, 256, 0, stream>>>(qbuf, kbuf, vtbuf, ctxbuf);

  gemm_bt_kernel<64, 1><<<dim3(32, 16), 256, 0, stream>>>(ctxbuf, Wot, x1buf, bo, x,
                                                          NROWS, 1024, 1024);

  ln_kernel<<<NROWS, 256, 0, stream>>>(x1buf, ln2s, ln2b, h2buf);

  gemm_bt_kernel<128, 2><<<dim3(32, 32), 256, 0, stream>>>(h2buf, W1t, gbuf, b1, nullptr,
                                                           NROWS, 4096, 1024);

  gemm_bt_kernel<64, 1><<<dim3(32, 16), 256, 0, stream>>>(gbuf, W2t, out, b2, x1buf,
                                                          NROWS, 1024, 4096);
}

// Round 3
// 287.944 us; speedup vs baseline: 1.5787x; 1.0802x over previous
//
#include <hip/hip_runtime.h>
#include <hip/hip_bf16.h>
#include <cstdint>

#define D_DIM 1024
#define S_DIM 2048
#define B_DIM 2
#define NROWS 4096
#define H_DIM 16
#define LOG2E 1.4426950408889634f
#define QSCALE (0.125f * LOG2E)

typedef __bf16 bf16x8 __attribute__((ext_vector_type(8)));
typedef float f32x4 __attribute__((ext_vector_type(4)));
typedef unsigned short u16x8 __attribute__((ext_vector_type(8)));

#define MFMA16(a, b, c) __builtin_amdgcn_mfma_f32_16x16x32_bf16(a, b, c, 0, 0, 0)

__device__ __forceinline__ void async_cp16(const void* g, void* lds) {
  __builtin_amdgcn_global_load_lds(
      (const __attribute__((address_space(1))) void*)(uintptr_t)g,
      (__attribute__((address_space(3))) void*)(uint32_t)(uintptr_t)lds, 16, 0, 0);
}

__device__ __forceinline__ unsigned short f2bf(float f) {
  __hip_bfloat16 h = __float2bfloat16(f);
  return __builtin_bit_cast(unsigned short, h);
}

__device__ __forceinline__ float bf2f(unsigned short u) {
  return __builtin_bit_cast(float, (unsigned int)u << 16);
}

__device__ __forceinline__ float gelu_f(float v) {
  return 0.5f * v * (1.f + tanhf(0.79788456f * (v + 0.044715f * v * v * v)));
}

// ---------------- fused weight transpose+cast: 6 matrices in one launch -----
struct TcArgs {
  const float* src[6];
  __hip_bfloat16* dst[6];
  int K[6];
  int N[6];
  int start[6];
};

__global__ __launch_bounds__(256) void transpose_cast6_kernel(TcArgs a) {
  __shared__ float tile[32][33];
  int bid = blockIdx.x, mi = 0;
#pragma unroll
  for (int i = 1; i < 6; i++)
    if (bid >= a.start[i]) mi = i;
  const float* W = a.src[mi];
  __hip_bfloat16* Wt = a.dst[mi];
  int K = a.K[mi], N = a.N[mi];
  int rel = bid - a.start[mi];
  int tilesx = N >> 5;
  int shift = (N == 4096) ? 7 : 5;
  int n0 = (rel & (tilesx - 1)) * 32, k0 = (rel >> shift) * 32;
  int tx = threadIdx.x, ty = threadIdx.y;
#pragma unroll
  for (int i = 0; i < 32; i += 8)
    tile[ty + i][tx] = W[(size_t)(k0 + ty + i) * N + n0 + tx];
  __syncthreads();
#pragma unroll
  for (int i = 0; i < 32; i += 8)
    Wt[(size_t)(n0 + ty + i) * K + k0 + tx] = __float2bfloat16(tile[tx][ty + i]);
}

// ---------------- layernorm (ddof=1) f32 -> bf16 -----------------------------
__global__ __launch_bounds__(256) void ln_kernel(
    const float* __restrict__ x, const float* __restrict__ sc,
    const float* __restrict__ bi, __hip_bfloat16* __restrict__ out) {
  int row = blockIdx.x, t = threadIdx.x;
  float4 v = ((const float4*)(x + (size_t)row * D_DIM))[t];
  float s = v.x + v.y + v.z + v.w;
  float ss = v.x * v.x + v.y * v.y + v.z * v.z + v.w * v.w;
#pragma unroll
  for (int off = 32; off > 0; off >>= 1) {
    s += __shfl_xor(s, off);
    ss += __shfl_xor(ss, off);
  }
  __shared__ float red[8];
  int wid = t >> 6;
  if ((t & 63) == 0) { red[wid] = s; red[4 + wid] = ss; }
  __syncthreads();
  s = red[0] + red[1] + red[2] + red[3];
  ss = red[4] + red[5] + red[6] + red[7];
  float mean = s * (1.f / 1024.f);
  float var = (ss - 1024.f * mean * mean) * (1.f / 1023.f);
  float inv = rsqrtf(var + 1e-5f);
  float4 scv = ((const float4*)sc)[t];
  float4 biv = ((const float4*)bi)[t];
  ushort4 o;
  o.x = f2bf(scv.x * (v.x - mean) * inv + biv.x);
  o.y = f2bf(scv.y * (v.y - mean) * inv + biv.y);
  o.z = f2bf(scv.z * (v.z - mean) * inv + biv.z);
  o.w = f2bf(scv.w * (v.w - mean) * inv + biv.w);
  ((ushort4*)(out + (size_t)row * D_DIM))[t] = o;
}

// ---------------- GEMM: C[M,N] = A[M,K] @ B, Bt[N][K] bf16, dbuf K-loop ------
// EPI 1: f32 out + bias + resid.  EPI 2: gelu->bf16 + bias.
// EPI 3: bf16 partial (split-K chunk kz) -> Cout[kz][M][N], no bias.
template <int BN, int EPI>
__global__ __launch_bounds__(256) void gemm_bt_kernel(
    const __hip_bfloat16* __restrict__ A, const __hip_bfloat16* __restrict__ Bt,
    void* __restrict__ Cout, const float* __restrict__ bias,
    const float* __restrict__ resid, int M, int N, int K, int kchunk) {
  constexpr int NBF = BN / 32;
  __shared__ __hip_bfloat16 As[2][128 * 32];
  __shared__ __hip_bfloat16 Bs[2][BN * 32];
  const int t = threadIdx.x;
  const int lane = t & 63, wid = t >> 6;
  const int ql = lane & 15, g = lane >> 4;
  const int m0 = blockIdx.x * 128, n0 = blockIdx.y * BN;
  const int kz = blockIdx.z;
  const int wm = (wid >> 1) * 64, wn = (wid & 1) * (BN / 2);
  f32x4 acc[4][NBF] = {};
  const int sr = t >> 2, sc8 = (t & 3) * 8;
  const __hip_bfloat16* ag = A + (size_t)(m0 + sr) * K + sc8 + (size_t)kz * kchunk;
  const __hip_bfloat16* bg = Bt + (size_t)(n0 + sr) * K + sc8 + (size_t)kz * kchunk;

  auto stage = [&](int buf, int k0) {
    async_cp16(ag + k0, (char*)&As[buf][0] + wid * 1024);
    async_cp16(ag + (size_t)64 * K + k0, (char*)&As[buf][0] + 4096 + wid * 1024);
    async_cp16(bg + k0, (char*)&Bs[buf][0] + wid * 1024);
    if constexpr (BN == 128)
      async_cp16(bg + (size_t)64 * K + k0, (char*)&Bs[buf][0] + 4096 + wid * 1024);
  };
  auto compute = [&](int buf) {
    bf16x8 af[4], bfr[NBF];
#pragma unroll
    for (int mb = 0; mb < 4; mb++)
      af[mb] = *(const bf16x8*)(&As[buf][(wm + mb * 16 + ql) * 32 + g * 8]);
#pragma unroll
    for (int nb = 0; nb < NBF; nb++)
      bfr[nb] = *(const bf16x8*)(&Bs[buf][(wn + nb * 16 + ql) * 32 + g * 8]);
#pragma unroll
    for (int mb = 0; mb < 4; mb++)
#pragma unroll
      for (int nb = 0; nb < NBF; nb++)
        acc[mb][nb] = MFMA16(af[mb], bfr[nb], acc[mb][nb]);
  };

  stage(0, 0);
  __syncthreads();  // compiler drains vmcnt before barrier -> tile 0 resident
  const int nsteps = kchunk >> 5;
  int cur = 0;
  for (int s = 0; s < nsteps - 1; ++s) {
    stage(cur ^ 1, (s + 1) * 32);  // prefetch next tile while computing this one
    compute(cur);
    __syncthreads();
    cur ^= 1;
  }
  compute(cur);

  const int rb = m0 + wm + (g << 2);
  const int cb = n0 + wn + ql;
#pragma unroll
  for (int mb = 0; mb < 4; mb++) {
#pragma unroll
    for (int nb = 0; nb < NBF; nb++) {
      int col = cb + nb * 16;
#pragma unroll
      for (int r = 0; r < 4; r++) {
        int row = rb + mb * 16 + r;
        float v = acc[mb][nb][r];
        if (EPI == 1) {
          ((float*)Cout)[(size_t)row * N + col] =
              v + bias[col] + resid[(size_t)row * N + col];
        } else if (EPI == 2) {
          ((__hip_bfloat16*)Cout)[(size_t)row * N + col] =
              __float2bfloat16(gelu_f(v + bias[col]));
        } else {
          ((unsigned short*)Cout)[(size_t)kz * ((size_t)M * N) + (size_t)row * N + col] =
              f2bf(v);
        }
      }
    }
  }
}

// ---------------- split-K reduce + bias + residual (f32 out) -----------------
__global__ __launch_bounds__(256) void ffn2_reduce_kernel(
    const unsigned short* __restrict__ parts, const float* __restrict__ bias,
    const float* __restrict__ resid, float* __restrict__ out) {
  const size_t i = ((size_t)blockIdx.x * 256 + threadIdx.x) * 8;
  const int col = (int)(i & 1023);
  float a[8];
  float4 r0 = *(const float4*)(resid + i);
  float4 r1 = *(const float4*)(resid + i + 4);
  float4 b0 = *(const float4*)(bias + col);
  float4 b1 = *(const float4*)(bias + col + 4);
  a[0] = r0.x + b0.x; a[1] = r0.y + b0.y; a[2] = r0.z + b0.z; a[3] = r0.w + b0.w;
  a[4] = r1.x + b1.x; a[5] = r1.y + b1.y; a[6] = r1.z + b1.z; a[7] = r1.w + b1.w;
#pragma unroll
  for (int c = 0; c < 4; c++) {
    u16x8 p = *(const u16x8*)(parts + (size_t)c * ((size_t)NROWS * 1024) + i);
#pragma unroll
    for (int j = 0; j < 8; j++) a[j] += bf2f(p[j]);
  }
  float4 o0 = {a[0], a[1], a[2], a[3]};
  float4 o1 = {a[4], a[5], a[6], a[7]};
  *(float4*)(out + i) = o0;
  *(float4*)(out + i + 4) = o1;
}

// ---------------- fused QKV GEMM: A[4096,1024] x {Wq,Wk,Wv}^T ----------------
// seg 0: Q *= 0.125*log2e -> qb.  seg 1: K -> kb.  seg 2: V transposed -> vt[b,h,d,s].
__global__ __launch_bounds__(256) void qkv_kernel(
    const __hip_bfloat16* __restrict__ A, const __hip_bfloat16* __restrict__ Wqt,
    const __hip_bfloat16* __restrict__ Wkt, const __hip_bfloat16* __restrict__ Wvt,
    __hip_bfloat16* __restrict__ qb, __hip_bfloat16* __restrict__ kb,
    unsigned short* __restrict__ vt) {
  __shared__ __hip_bfloat16 As[2][128 * 32];
  __shared__ __hip_bfloat16 Bs[2][128 * 32];
  const int t = threadIdx.x;
  const int lane = t & 63, wid = t >> 6;
  const int ql = lane & 15, g = lane >> 4;
  const int seg = blockIdx.y >> 3;
  const int n0 = (blockIdx.y & 7) * 128;
  const __hip_bfloat16* Bt = seg == 0 ? Wqt : (seg == 1 ? Wkt : Wvt);
  const int m0 = blockIdx.x * 128;
  const int wm = (wid >> 1) * 64, wn = (wid & 1) * 64;
  f32x4 acc[4][4] = {};
  const int sr = t >> 2, sc8 = (t & 3) * 8;
  const __hip_bfloat16* ag = A + (size_t)(m0 + sr) * 1024 + sc8;
  const __hip_bfloat16* bg = Bt + (size_t)(n0 + sr) * 1024 + sc8;

  auto stage = [&](int buf, int k0) {
    async_cp16(ag + k0, (char*)&As[buf][0] + wid * 1024);
    async_cp16(ag + (size_t)64 * 1024 + k0, (char*)&As[buf][0] + 4096 + wid * 1024);
    async_cp16(bg + k0, (char*)&Bs[buf][0] + wid * 1024);
    async_cp16(bg + (size_t)64 * 1024 + k0, (char*)&Bs[buf][0] + 4096 + wid * 1024);
  };
  auto compute = [&](int buf) {
    bf16x8 af[4], bfr[4];
#pragma unroll
    for (int mb = 0; mb < 4; mb++)
      af[mb] = *(const bf16x8*)(&As[buf][(wm + mb * 16 + ql) * 32 + g * 8]);
#pragma unroll
    for (int nb = 0; nb < 4; nb++)
      bfr[nb] = *(const bf16x8*)(&Bs[buf][(wn + nb * 16 + ql) * 32 + g * 8]);
#pragma unroll
    for (int mb = 0; mb < 4; mb++)
#pragma unroll
      for (int nb = 0; nb < 4; nb++)
        acc[mb][nb] = MFMA16(af[mb], bfr[nb], acc[mb][nb]);
  };

  stage(0, 0);
  __syncthreads();
  int cur = 0;
  for (int s = 0; s < 31; ++s) {
    stage(cur ^ 1, (s + 1) * 32);
    compute(cur);
    __syncthreads();
    cur ^= 1;
  }
  compute(cur);

  const int rb = m0 + wm + (g << 2);
  if (seg < 2) {
    __hip_bfloat16* Ob = seg == 0 ? qb : kb;
    const float sc = seg == 0 ? QSCALE : 1.f;
#pragma unroll
    for (int mb = 0; mb < 4; mb++)
#pragma unroll
      for (int nb = 0; nb < 4; nb++) {
        int col = n0 + wn + nb * 16 + ql;
#pragma unroll
        for (int r = 0; r < 4; r++)
          Ob[(size_t)(rb + mb * 16 + r) * 1024 + col] =
              __float2bfloat16(acc[mb][nb][r] * sc);
      }
  } else {
#pragma unroll
    for (int mb = 0; mb < 4; mb++)
#pragma unroll
      for (int nb = 0; nb < 4; nb++) {
        int col = n0 + wn + nb * 16 + ql;
        int h = col >> 6, dh = col & 63;
        int row0 = rb + mb * 16;
        int bb = row0 >> 11, s0 = row0 & 2047;
        ushort4 pk;
        pk.x = f2bf(acc[mb][nb][0]);
        pk.y = f2bf(acc[mb][nb][1]);
        pk.z = f2bf(acc[mb][nb][2]);
        pk.w = f2bf(acc[mb][nb][3]);
        *(ushort4*)(vt + (((size_t)(bb * 16 + h) * 64 + dh) << 11) + s0) = pk;
      }
  }
}

// ---------------- causal flash attention: 1 wave per 32 q-rows ---------------
// Q pre-scaled by 0.125*log2e (exp2-space). K row-major [b,s,h*64+d]; V pre-
// transposed vt[b,h,d,s]. P via per-wave LDS, XOR-swizzled b64 writes/b128 reads.
__global__ __launch_bounds__(256) void attn_kernel(
    const __hip_bfloat16* __restrict__ Q, const __hip_bfloat16* __restrict__ Kb,
    const __hip_bfloat16* __restrict__ Vt, __hip_bfloat16* __restrict__ ctx) {
  __shared__ alignas(16) unsigned short Ps[4][32 * 32];
  const int t = threadIdx.x;
  const int lane = t & 63, wid = t >> 6;
  const int ql = lane & 15, g = lane >> 4;
  const int wg = ((blockIdx.x & 7) << 6) | (blockIdx.x >> 3);  // XCD swizzle
  const int bh = wg >> 4, qig = wg & 15;
  const int qi = wid * 16 + qig;  // balance work across waves of a block
  const int q0 = qi * 32;
  const int b = bh >> 4, hh = bh & 15;
  const __hip_bfloat16* qp = Q + (size_t)b * S_DIM * D_DIM + hh * 64;
  const __hip_bfloat16* kp = Kb + (size_t)b * S_DIM * D_DIM + hh * 64;
  const __hip_bfloat16* vp = Vt + (size_t)bh * 64 * S_DIM;
  unsigned short* Pw = Ps[wid];
  const int sw = (ql & 3) << 4;

  bf16x8 qf[2][2];
#pragma unroll
  for (int qs = 0; qs < 2; qs++)
#pragma unroll
    for (int hf = 0; hf < 2; hf++)
      qf[qs][hf] = *(const bf16x8*)(qp + (size_t)(q0 + qs * 16 + ql) * D_DIM + hf * 32 + g * 8);

  float m[2] = {-3.0e38f, -3.0e38f}, lsum[2] = {0.f, 0.f};
  f32x4 acc[4][2] = {};
  const f32x4 z4 = {0.f, 0.f, 0.f, 0.f};
  const int kvend = q0 + 32;

  bf16x8 ka[2][2];
#pragma unroll
  for (int ks = 0; ks < 2; ks++)
#pragma unroll
    for (int hf = 0; hf < 2; hf++)
      ka[ks][hf] = *(const bf16x8*)(kp + (size_t)(ks * 16 + ql) * D_DIM + hf * 32 + g * 8);

  for (int kv0 = 0; kv0 < kvend; kv0 += 32) {
    bf16x8 va[4];
#pragma unroll
    for (int db = 0; db < 4; db++)
      va[db] = *(const bf16x8*)(vp + (size_t)(db * 16 + ql) * S_DIM + kv0 + 8 * g);

    const int kvn = (kv0 + 32 < kvend) ? kv0 + 32 : kv0;
    bf16x8 kn[2][2];
#pragma unroll
    for (int ks = 0; ks < 2; ks++)
#pragma unroll
      for (int hf = 0; hf < 2; hf++)
        kn[ks][hf] = *(const bf16x8*)(kp + (size_t)(kvn + ks * 16 + ql) * D_DIM + hf * 32 + g * 8);

    f32x4 st[2][2];
#pragma unroll
    for (int ks = 0; ks < 2; ks++)
#pragma unroll
      for (int qs = 0; qs < 2; qs++)
        st[ks][qs] = MFMA16(ka[ks][1], qf[qs][1], MFMA16(ka[ks][0], qf[qs][0], z4));

    if (kv0 + 31 > q0) {  // only the diagonal tile needs masking
#pragma unroll
      for (int ks = 0; ks < 2; ks++)
#pragma unroll
        for (int qs = 0; qs < 2; qs++)
#pragma unroll
          for (int r = 0; r < 4; r++)
            if (kv0 + ks * 16 + 4 * g + r > q0 + qs * 16 + ql) st[ks][qs][r] = -3.0e38f;
    }

#pragma unroll
    for (int qs = 0; qs < 2; qs++) {
      float tm = -3.0e38f;
#pragma unroll
      for (int r = 0; r < 4; r++) tm = fmaxf(tm, fmaxf(st[0][qs][r], st[1][qs][r]));
      tm = fmaxf(tm, __shfl_xor(tm, 16));
      tm = fmaxf(tm, __shfl_xor(tm, 32));
      const float mn = fmaxf(m[qs], tm);
      const float alpha = exp2f(m[qs] - mn);
      float p0[4], p1[4], ps = 0.f;
#pragma unroll
      for (int r = 0; r < 4; r++) {
        p0[r] = exp2f(st[0][qs][r] - mn);
        p1[r] = exp2f(st[1][qs][r] - mn);
        ps += p0[r] + p1[r];
      }
      ps += __shfl_xor(ps, 16);
      ps += __shfl_xor(ps, 32);
      lsum[qs] = lsum[qs] * alpha + ps;
      m[qs] = mn;
#pragma unroll
      for (int db = 0; db < 4; db++) acc[db][qs] *= alpha;
      const int q = qs * 16 + ql;
      ushort4 pk0, pk1;
      pk0.x = f2bf(p0[0]); pk0.y = f2bf(p0[1]); pk0.z = f2bf(p0[2]); pk0.w = f2bf(p0[3]);
      pk1.x = f2bf(p1[0]); pk1.y = f2bf(p1[1]); pk1.z = f2bf(p1[2]); pk1.w = f2bf(p1[3]);
      *(ushort4*)((char*)Pw + q * 64 + ((8 * g) ^ sw)) = pk0;
      *(ushort4*)((char*)Pw + q * 64 + ((32 + 8 * g) ^ sw)) = pk1;
    }

    bf16x8 pb[2];
#pragma unroll
    for (int qs = 0; qs < 2; qs++)
      pb[qs] = *(const bf16x8*)((const char*)Pw + (qs * 16 + ql) * 64 + ((16 * g) ^ sw));
#pragma unroll
    for (int db = 0; db < 4; db++)
#pragma unroll
      for (int qs = 0; qs < 2; qs++)
        acc[db][qs] = MFMA16(va[db], pb[qs], acc[db][qs]);
#pragma unroll
    for (int ks = 0; ks < 2; ks++)
#pragma unroll
      for (int hf = 0; hf < 2; hf++)
        ka[ks][hf] = kn[ks][hf];
  }

#pragma unroll
  for (int qs = 0; qs < 2; qs++) {
    const float inv = 1.f / lsum[qs];
    const int q = q0 + qs * 16 + ql;
    unsigned short* cp = (unsigned short*)ctx + (size_t)(b * S_DIM + q) * D_DIM + hh * 64;
#pragma unroll
    for (int db = 0; db < 4; db++)
#pragma unroll
      for (int i = 0; i < 2; i++) {
        unsigned int lo = f2bf(acc[db][qs][2 * i] * inv);
        unsigned int hi = f2bf(acc[db][qs][2 * i + 1] * inv);
        *(unsigned int*)(cp + db * 16 + 4 * g + 2 * i) = lo | (hi << 16);
      }
  }
}

// ---------------- orchestration ----------------------------------------------
extern "C" void kernel_launch(void* const* d_in, const int* in_sizes, int n_in,
                              void* d_out, int out_size, void* d_ws, size_t ws_size,
                              hipStream_t stream) {
  const float* x = (const float*)d_in[0];
  const float* Wq = (const float*)d_in[1];
  const float* Wk = (const float*)d_in[2];
  const float* Wv = (const float*)d_in[3];
  const float* Wo = (const float*)d_in[4];
  const float* bo = (const float*)d_in[5];
  const float* W1 = (const float*)d_in[6];
  const float* b1 = (const float*)d_in[7];
  const float* W2 = (const float*)d_in[8];
  const float* b2 = (const float*)d_in[9];
  const float* ln1s = (const float*)d_in[10];
  const float* ln1b = (const float*)d_in[11];
  const float* ln2s = (const float*)d_in[12];
  const float* ln2b = (const float*)d_in[13];
  float* out = (float*)d_out;

  char* p = (char*)d_ws;
  auto take = [&](size_t n) { char* r = p; p += (n + 255) & ~(size_t)255; return r; };
  __hip_bfloat16* Wqt = (__hip_bfloat16*)take((size_t)1024 * 1024 * 2);
  __hip_bfloat16* Wkt = (__hip_bfloat16*)take((size_t)1024 * 1024 * 2);
  __hip_bfloat16* Wvt = (__hip_bfloat16*)take((size_t)1024 * 1024 * 2);
  __hip_bfloat16* Wot = (__hip_bfloat16*)take((size_t)1024 * 1024 * 2);
  __hip_bfloat16* W1t = (__hip_bfloat16*)take((size_t)4096 * 1024 * 2);
  __hip_bfloat16* W2t = (__hip_bfloat16*)take((size_t)4096 * 1024 * 2);
  // hbuf..vtbuf are contiguous (each 8 MiB, 256B-aligned) and dead by FFN2
  // time -> reused as the 4 split-K bf16 partial buffers.
  __hip_bfloat16* hbuf = (__hip_bfloat16*)take((size_t)NROWS * 1024 * 2);
  __hip_bfloat16* qbuf = (__hip_bfloat16*)take((size_t)NROWS * 1024 * 2);
  __hip_bfloat16* kbuf = (__hip_bfloat16*)take((size_t)NROWS * 1024 * 2);
  __hip_bfloat16* vtbuf = (__hip_bfloat16*)take((size_t)NROWS * 1024 * 2);
  __hip_bfloat16* ctxbuf = (__hip_bfloat16*)take((size_t)NROWS * 1024 * 2);
  float* x1buf = (float*)take((size_t)NROWS * 1024 * 4);
  __hip_bfloat16* h2buf = (__hip_bfloat16*)take((size_t)NROWS * 1024 * 2);
  __hip_bfloat16* gbuf = (__hip_bfloat16*)take((size_t)NROWS * 4096 * 2);
  unsigned short* parts = (unsigned short*)hbuf;

  TcArgs ta;
  ta.src[0] = Wq;  ta.dst[0] = Wqt;  ta.K[0] = 1024; ta.N[0] = 1024; ta.start[0] = 0;
  ta.src[1] = Wk;  ta.dst[1] = Wkt;  ta.K[1] = 1024; ta.N[1] = 1024; ta.start[1] = 1024;
  ta.src[2] = Wv;  ta.dst[2] = Wvt;  ta.K[2] = 1024; ta.N[2] = 1024; ta.start[2] = 2048;
  ta.src[3] = Wo;  ta.dst[3] = Wot;  ta.K[3] = 1024; ta.N[3] = 1024; ta.start[3] = 3072;
  ta.src[4] = W1;  ta.dst[4] = W1t;  ta.K[4] = 1024; ta.N[4] = 4096; ta.start[4] = 4096;
  ta.src[5] = W2;  ta.dst[5] = W2t;  ta.K[5] = 4096; ta.N[5] = 1024; ta.start[5] = 8192;
  transpose_cast6_kernel<<<12288, dim3(32, 8), 0, stream>>>(ta);

  ln_kernel<<<NROWS, 256, 0, stream>>>(x, ln1s, ln1b, hbuf);

  qkv_kernel<<<dim3(32, 24), 256, 0, stream>>>(hbuf, Wqt, Wkt, Wvt, qbuf, kbuf,
                                               (unsigned short*)vtbuf);

  attn_kernel<<<512, 256, 0, stream>>>(qbuf, kbuf, vtbuf, ctxbuf);

  gemm_bt_kernel<64, 1><<<dim3(32, 16, 1), 256, 0, stream>>>(
      ctxbuf, Wot, x1buf, bo, x, NROWS, 1024, 1024, 1024);

  ln_kernel<<<NROWS, 256, 0, stream>>>(x1buf, ln2s, ln2b, h2buf);

  gemm_bt_kernel<128, 2><<<dim3(32, 32, 1), 256, 0, stream>>>(
      h2buf, W1t, gbuf, b1, nullptr, NROWS, 4096, 1024, 1024);

  gemm_bt_kernel<128, 3><<<dim3(32, 8, 4), 256, 0, stream>>>(
      gbuf, W2t, parts, nullptr, nullptr, NROWS, 1024, 4096, 1024);

  ffn2_reduce_kernel<<<2048, 256, 0, stream>>>(parts, b2, x1buf, out);
}

// Round 4
// 245.517 us; speedup vs baseline: 1.8515x; 1.1728x over previous
//
#include <hip/hip_runtime.h>
#include <hip/hip_bf16.h>
#include <cstdint>

#define D_DIM 1024
#define S_DIM 2048
#define B_DIM 2
#define NROWS 4096
#define H_DIM 16
#define LOG2E 1.4426950408889634f
#define QSCALE (0.125f * LOG2E)

typedef __bf16 bf16x8 __attribute__((ext_vector_type(8)));
typedef float f32x4 __attribute__((ext_vector_type(4)));
typedef unsigned short u16x8 __attribute__((ext_vector_type(8)));

#define MFMA16(a, b, c) __builtin_amdgcn_mfma_f32_16x16x32_bf16(a, b, c, 0, 0, 0)

__device__ __forceinline__ void async_cp16(const void* g, void* lds) {
  __builtin_amdgcn_global_load_lds(
      (const __attribute__((address_space(1))) void*)(uintptr_t)g,
      (__attribute__((address_space(3))) void*)(uint32_t)(uintptr_t)lds, 16, 0, 0);
}

__device__ __forceinline__ unsigned short f2bf(float f) {
  __hip_bfloat16 h = __float2bfloat16(f);
  return __builtin_bit_cast(unsigned short, h);
}

__device__ __forceinline__ float bf2f(unsigned short u) {
  return __builtin_bit_cast(float, (unsigned int)u << 16);
}

__device__ __forceinline__ float gelu_f(float v) {
  return 0.5f * v * (1.f + tanhf(0.79788456f * (v + 0.044715f * v * v * v)));
}

// ---------------- fused weight transpose+cast: 6 matrices in one launch -----
struct TcArgs {
  const float* src[6];
  __hip_bfloat16* dst[6];
  int K[6];
  int N[6];
  int start[6];
};

__global__ __launch_bounds__(256) void transpose_cast6_kernel(TcArgs a) {
  __shared__ float tile[32][33];
  int bid = blockIdx.x, mi = 0;
#pragma unroll
  for (int i = 1; i < 6; i++)
    if (bid >= a.start[i]) mi = i;
  const float* W = a.src[mi];
  __hip_bfloat16* Wt = a.dst[mi];
  int K = a.K[mi], N = a.N[mi];
  int rel = bid - a.start[mi];
  int tilesx = N >> 5;
  int shift = (N == 4096) ? 7 : 5;
  int n0 = (rel & (tilesx - 1)) * 32, k0 = (rel >> shift) * 32;
  int tx = threadIdx.x, ty = threadIdx.y;
#pragma unroll
  for (int i = 0; i < 32; i += 8)
    tile[ty + i][tx] = W[(size_t)(k0 + ty + i) * N + n0 + tx];
  __syncthreads();
#pragma unroll
  for (int i = 0; i < 32; i += 8)
    Wt[(size_t)(n0 + ty + i) * K + k0 + tx] = __float2bfloat16(tile[tx][ty + i]);
}

// ---------------- layernorm (ddof=1) f32 -> bf16 -----------------------------
__global__ __launch_bounds__(256) void ln_kernel(
    const float* __restrict__ x, const float* __restrict__ sc,
    const float* __restrict__ bi, __hip_bfloat16* __restrict__ out) {
  int row = blockIdx.x, t = threadIdx.x;
  float4 v = ((const float4*)(x + (size_t)row * D_DIM))[t];
  float s = v.x + v.y + v.z + v.w;
  float ss = v.x * v.x + v.y * v.y + v.z * v.z + v.w * v.w;
#pragma unroll
  for (int off = 32; off > 0; off >>= 1) {
    s += __shfl_xor(s, off);
    ss += __shfl_xor(ss, off);
  }
  __shared__ float red[8];
  int wid = t >> 6;
  if ((t & 63) == 0) { red[wid] = s; red[4 + wid] = ss; }
  __syncthreads();
  s = red[0] + red[1] + red[2] + red[3];
  ss = red[4] + red[5] + red[6] + red[7];
  float mean = s * (1.f / 1024.f);
  float var = (ss - 1024.f * mean * mean) * (1.f / 1023.f);
  float inv = rsqrtf(var + 1e-5f);
  float4 scv = ((const float4*)sc)[t];
  float4 biv = ((const float4*)bi)[t];
  ushort4 o;
  o.x = f2bf(scv.x * (v.x - mean) * inv + biv.x);
  o.y = f2bf(scv.y * (v.y - mean) * inv + biv.y);
  o.z = f2bf(scv.z * (v.z - mean) * inv + biv.z);
  o.w = f2bf(scv.w * (v.w - mean) * inv + biv.w);
  ((ushort4*)(out + (size_t)row * D_DIM))[t] = o;
}

// ---------------- GEMM: C[M,N] = A[M,K] @ B, Bt[N][K] bf16, dbuf K-loop ------
// EPI 1: f32 out + bias + resid.  EPI 2: gelu->bf16 + bias.
// EPI 3: bf16 partial (split-K chunk kz) -> Cout[kz][M][N], no bias.
template <int BN, int EPI>
__global__ __launch_bounds__(256) void gemm_bt_kernel(
    const __hip_bfloat16* __restrict__ A, const __hip_bfloat16* __restrict__ Bt,
    void* __restrict__ Cout, const float* __restrict__ bias,
    const float* __restrict__ resid, int M, int N, int K, int kchunk) {
  constexpr int NBF = BN / 32;
  __shared__ __hip_bfloat16 As[2][128 * 32];
  __shared__ __hip_bfloat16 Bs[2][BN * 32];
  const int t = threadIdx.x;
  const int lane = t & 63, wid = t >> 6;
  const int ql = lane & 15, g = lane >> 4;
  const int m0 = blockIdx.x * 128, n0 = blockIdx.y * BN;
  const int kz = blockIdx.z;
  const int wm = (wid >> 1) * 64, wn = (wid & 1) * (BN / 2);
  f32x4 acc[4][NBF] = {};
  const int sr = t >> 2, sc8 = (t & 3) * 8;
  const __hip_bfloat16* ag = A + (size_t)(m0 + sr) * K + sc8 + (size_t)kz * kchunk;
  const __hip_bfloat16* bg = Bt + (size_t)(n0 + sr) * K + sc8 + (size_t)kz * kchunk;

  auto stage = [&](int buf, int k0) {
    async_cp16(ag + k0, (char*)&As[buf][0] + wid * 1024);
    async_cp16(ag + (size_t)64 * K + k0, (char*)&As[buf][0] + 4096 + wid * 1024);
    async_cp16(bg + k0, (char*)&Bs[buf][0] + wid * 1024);
    if constexpr (BN == 128)
      async_cp16(bg + (size_t)64 * K + k0, (char*)&Bs[buf][0] + 4096 + wid * 1024);
  };
  auto compute = [&](int buf) {
    bf16x8 af[4], bfr[NBF];
#pragma unroll
    for (int mb = 0; mb < 4; mb++)
      af[mb] = *(const bf16x8*)(&As[buf][(wm + mb * 16 + ql) * 32 + g * 8]);
#pragma unroll
    for (int nb = 0; nb < NBF; nb++)
      bfr[nb] = *(const bf16x8*)(&Bs[buf][(wn + nb * 16 + ql) * 32 + g * 8]);
#pragma unroll
    for (int mb = 0; mb < 4; mb++)
#pragma unroll
      for (int nb = 0; nb < NBF; nb++)
        acc[mb][nb] = MFMA16(af[mb], bfr[nb], acc[mb][nb]);
  };

  stage(0, 0);
  __syncthreads();
  const int nsteps = kchunk >> 5;
  int cur = 0;
  for (int s = 0; s < nsteps - 1; ++s) {
    stage(cur ^ 1, (s + 1) * 32);
    compute(cur);
    __syncthreads();
    cur ^= 1;
  }
  compute(cur);

  const int rb = m0 + wm + (g << 2);
  const int cb = n0 + wn + ql;
#pragma unroll
  for (int mb = 0; mb < 4; mb++) {
#pragma unroll
    for (int nb = 0; nb < NBF; nb++) {
      int col = cb + nb * 16;
#pragma unroll
      for (int r = 0; r < 4; r++) {
        int row = rb + mb * 16 + r;
        float v = acc[mb][nb][r];
        if (EPI == 1) {
          ((float*)Cout)[(size_t)row * N + col] =
              v + bias[col] + resid[(size_t)row * N + col];
        } else if (EPI == 2) {
          ((__hip_bfloat16*)Cout)[(size_t)row * N + col] =
              __float2bfloat16(gelu_f(v + bias[col]));
        } else {
          ((unsigned short*)Cout)[(size_t)kz * ((size_t)M * N) + (size_t)row * N + col] =
              f2bf(v);
        }
      }
    }
  }
}

// ---------------- split-K reduce + bias + residual (f32 out) -----------------
__global__ __launch_bounds__(256) void ffn2_reduce_kernel(
    const unsigned short* __restrict__ parts, const float* __restrict__ bias,
    const float* __restrict__ resid, float* __restrict__ out) {
  const size_t i = ((size_t)blockIdx.x * 256 + threadIdx.x) * 8;
  const int col = (int)(i & 1023);
  float a[8];
  float4 r0 = *(const float4*)(resid + i);
  float4 r1 = *(const float4*)(resid + i + 4);
  float4 b0 = *(const float4*)(bias + col);
  float4 b1 = *(const float4*)(bias + col + 4);
  a[0] = r0.x + b0.x; a[1] = r0.y + b0.y; a[2] = r0.z + b0.z; a[3] = r0.w + b0.w;
  a[4] = r1.x + b1.x; a[5] = r1.y + b1.y; a[6] = r1.z + b1.z; a[7] = r1.w + b1.w;
#pragma unroll
  for (int c = 0; c < 4; c++) {
    u16x8 p = *(const u16x8*)(parts + (size_t)c * ((size_t)NROWS * 1024) + i);
#pragma unroll
    for (int j = 0; j < 8; j++) a[j] += bf2f(p[j]);
  }
  float4 o0 = {a[0], a[1], a[2], a[3]};
  float4 o1 = {a[4], a[5], a[6], a[7]};
  *(float4*)(out + i) = o0;
  *(float4*)(out + i + 4) = o1;
}

// ---------------- fused QKV GEMM: A[4096,1024] x {Wq,Wk,Wv}^T ----------------
// seg 0: Q *= 0.125*log2e -> qb.  seg 1: K -> kb.  seg 2: V transposed -> vt[b,h,d,s].
__global__ __launch_bounds__(256) void qkv_kernel(
    const __hip_bfloat16* __restrict__ A, const __hip_bfloat16* __restrict__ Wqt,
    const __hip_bfloat16* __restrict__ Wkt, const __hip_bfloat16* __restrict__ Wvt,
    __hip_bfloat16* __restrict__ qb, __hip_bfloat16* __restrict__ kb,
    unsigned short* __restrict__ vt) {
  __shared__ __hip_bfloat16 As[2][128 * 32];
  __shared__ __hip_bfloat16 Bs[2][128 * 32];
  const int t = threadIdx.x;
  const int lane = t & 63, wid = t >> 6;
  const int ql = lane & 15, g = lane >> 4;
  const int seg = blockIdx.y >> 3;
  const int n0 = (blockIdx.y & 7) * 128;
  const __hip_bfloat16* Bt = seg == 0 ? Wqt : (seg == 1 ? Wkt : Wvt);
  const int m0 = blockIdx.x * 128;
  const int wm = (wid >> 1) * 64, wn = (wid & 1) * 64;
  f32x4 acc[4][4] = {};
  const int sr = t >> 2, sc8 = (t & 3) * 8;
  const __hip_bfloat16* ag = A + (size_t)(m0 + sr) * 1024 + sc8;
  const __hip_bfloat16* bg = Bt + (size_t)(n0 + sr) * 1024 + sc8;

  auto stage = [&](int buf, int k0) {
    async_cp16(ag + k0, (char*)&As[buf][0] + wid * 1024);
    async_cp16(ag + (size_t)64 * 1024 + k0, (char*)&As[buf][0] + 4096 + wid * 1024);
    async_cp16(bg + k0, (char*)&Bs[buf][0] + wid * 1024);
    async_cp16(bg + (size_t)64 * 1024 + k0, (char*)&Bs[buf][0] + 4096 + wid * 1024);
  };
  auto compute = [&](int buf) {
    bf16x8 af[4], bfr[4];
#pragma unroll
    for (int mb = 0; mb < 4; mb++)
      af[mb] = *(const bf16x8*)(&As[buf][(wm + mb * 16 + ql) * 32 + g * 8]);
#pragma unroll
    for (int nb = 0; nb < 4; nb++)
      bfr[nb] = *(const bf16x8*)(&Bs[buf][(wn + nb * 16 + ql) * 32 + g * 8]);
#pragma unroll
    for (int mb = 0; mb < 4; mb++)
#pragma unroll
      for (int nb = 0; nb < 4; nb++)
        acc[mb][nb] = MFMA16(af[mb], bfr[nb], acc[mb][nb]);
  };

  stage(0, 0);
  __syncthreads();
  int cur = 0;
  for (int s = 0; s < 31; ++s) {
    stage(cur ^ 1, (s + 1) * 32);
    compute(cur);
    __syncthreads();
    cur ^= 1;
  }
  compute(cur);

  const int rb = m0 + wm + (g << 2);
  if (seg < 2) {
    __hip_bfloat16* Ob = seg == 0 ? qb : kb;
    const float sc = seg == 0 ? QSCALE : 1.f;
#pragma unroll
    for (int mb = 0; mb < 4; mb++)
#pragma unroll
      for (int nb = 0; nb < 4; nb++) {
        int col = n0 + wn + nb * 16 + ql;
#pragma unroll
        for (int r = 0; r < 4; r++)
          Ob[(size_t)(rb + mb * 16 + r) * 1024 + col] =
              __float2bfloat16(acc[mb][nb][r] * sc);
      }
  } else {
#pragma unroll
    for (int mb = 0; mb < 4; mb++)
#pragma unroll
      for (int nb = 0; nb < 4; nb++) {
        int col = n0 + wn + nb * 16 + ql;
        int h = col >> 6, dh = col & 63;
        int row0 = rb + mb * 16;
        int bb = row0 >> 11, s0 = row0 & 2047;
        ushort4 pk;
        pk.x = f2bf(acc[mb][nb][0]);
        pk.y = f2bf(acc[mb][nb][1]);
        pk.z = f2bf(acc[mb][nb][2]);
        pk.w = f2bf(acc[mb][nb][3]);
        *(ushort4*)(vt + (((size_t)(bb * 16 + h) * 64 + dh) << 11) + s0) = pk;
      }
  }
}

// ---------------- causal flash attention, LDS-staged K/V ---------------------
// Block = 4 waves x 16 q-rows (64-row q-tile). K tile [64 kv][64 d] and V^T
// tile [64 d][64 kv] staged via global_load_lds (dbuf, stage-before-compute),
// XOR-swizzled chunks (inverse-swizzled global source, swizzled LDS reads).
// Q pre-scaled by 0.125*log2e (exp2-space softmax). Defer-max THR=8.
__global__ __launch_bounds__(256) void attn_kernel(
    const __hip_bfloat16* __restrict__ Q, const __hip_bfloat16* __restrict__ Kb,
    const __hip_bfloat16* __restrict__ Vt, __hip_bfloat16* __restrict__ ctx) {
  __shared__ unsigned short Ks[2][64 * 64];
  __shared__ unsigned short Vs[2][64 * 64];
  __shared__ alignas(16) unsigned short Ps[4][16 * 64];
  const int t = threadIdx.x;
  const int lane = t & 63, wid = t >> 6;
  const int ql = lane & 15, g = lane >> 4;
  // balance: the 4 scheduling rounds of 256 blocks get complementary qt sets
  const int bid = blockIdx.x;
  const int r4 = bid >> 8, k8 = (bid >> 5) & 7, bh = bid & 31;
  const int qt = (r4 == 0) ? 31 - k8 : (r4 == 1) ? 16 + k8 : (r4 == 2) ? 15 - k8 : k8;
  const int b = bh >> 4, hh = bh & 15;
  const int wq0 = qt * 64 + wid * 16;
  const __hip_bfloat16* qp = Q + (size_t)b * S_DIM * D_DIM + hh * 64;
  const __hip_bfloat16* kp = Kb + (size_t)b * S_DIM * D_DIM + hh * 64;
  const __hip_bfloat16* vp = Vt + (size_t)bh * 64 * S_DIM;
  const int kvend = qt * 64 + 64;
  const int swz = (ql & 7) << 4;
  const f32x4 z4 = {0.f, 0.f, 0.f, 0.f};

  auto stageKV = [&](int buf, int kv0) {
    const int sub = lane >> 3, c = lane & 7;
#pragma unroll
    for (int i = 0; i < 2; i++) {
      const int row = wid * 16 + i * 8 + sub;
      const int cs = (c ^ (row & 7)) * 8;  // inverse-swizzled source chunk
      async_cp16(kp + (size_t)(kv0 + row) * D_DIM + cs,
                 (char*)&Ks[buf][0] + (wid * 16 + i * 8) * 128);
      async_cp16(vp + (size_t)row * S_DIM + kv0 + cs,
                 (char*)&Vs[buf][0] + (wid * 16 + i * 8) * 128);
    }
  };

  bf16x8 qf[2];
#pragma unroll
  for (int hf = 0; hf < 2; hf++)
    qf[hf] = *(const bf16x8*)(qp + (size_t)(wq0 + ql) * D_DIM + hf * 32 + g * 8);

  float m = -3.0e38f, lsum = 0.f;
  f32x4 acc[4] = {};
  unsigned short* Pw = Ps[wid];

  stageKV(0, 0);
  __syncthreads();
  int cur = 0;
  for (int kv0 = 0; kv0 < kvend; kv0 += 64) {
    if (kv0 + 64 < kvend) stageKV(cur ^ 1, kv0 + 64);

    if (kv0 <= wq0 + 15) {  // wave has at least one unmasked (q,kv) pair
      const char* Kt = (const char*)&Ks[cur][0];
      f32x4 st[4];
#pragma unroll
      for (int ks = 0; ks < 4; ks++) {
        bf16x8 k0 = *(const bf16x8*)(Kt + (ks * 16 + ql) * 128 + ((g * 16) ^ swz));
        bf16x8 k1 = *(const bf16x8*)(Kt + (ks * 16 + ql) * 128 + (((4 + g) * 16) ^ swz));
        st[ks] = MFMA16(k1, qf[1], MFMA16(k0, qf[0], z4));
      }
      if (kv0 + 63 > wq0) {  // diagonal: apply causal mask
#pragma unroll
        for (int ks = 0; ks < 4; ks++)
#pragma unroll
          for (int r = 0; r < 4; r++)
            if (kv0 + ks * 16 + 4 * g + r > wq0 + ql) st[ks][r] = -3.0e38f;
      }
      float tm = -3.0e38f;
#pragma unroll
      for (int ks = 0; ks < 4; ks++)
#pragma unroll
        for (int r = 0; r < 4; r++) tm = fmaxf(tm, st[ks][r]);
      tm = fmaxf(tm, __shfl_xor(tm, 16));
      tm = fmaxf(tm, __shfl_xor(tm, 32));
      if (!__all(tm <= m + 8.f)) {  // defer-max: rescale only on real growth
        const float mn = fmaxf(m, tm);
        const float alpha = exp2f(m - mn);
        lsum *= alpha;
#pragma unroll
        for (int db = 0; db < 4; db++) acc[db] *= alpha;
        m = mn;
      }
      float psum = 0.f;
#pragma unroll
      for (int ks = 0; ks < 4; ks++) {
        float p0 = exp2f(st[ks][0] - m), p1 = exp2f(st[ks][1] - m);
        float p2 = exp2f(st[ks][2] - m), p3 = exp2f(st[ks][3] - m);
        psum += (p0 + p1) + (p2 + p3);
        ushort4 pk;
        pk.x = f2bf(p0); pk.y = f2bf(p1); pk.z = f2bf(p2); pk.w = f2bf(p3);
        *(ushort4*)((char*)Pw + ql * 128 + ((ks * 32 + 8 * g) ^ swz)) = pk;
      }
      psum += __shfl_xor(psum, 16);
      psum += __shfl_xor(psum, 32);
      lsum += psum;

      const char* Vtl = (const char*)&Vs[cur][0];
#pragma unroll
      for (int ksl = 0; ksl < 2; ksl++) {
        bf16x8 pb = *(const bf16x8*)((const char*)Pw + ql * 128 + ((ksl * 64 + 16 * g) ^ swz));
#pragma unroll
        for (int db = 0; db < 4; db++) {
          bf16x8 va = *(const bf16x8*)(Vtl + (db * 16 + ql) * 128 + (((ksl * 4 + g) * 16) ^ swz));
          acc[db] = MFMA16(va, pb, acc[db]);
        }
      }
    }
    __syncthreads();
    cur ^= 1;
  }

  const float inv = 1.f / lsum;
  unsigned short* cp = (unsigned short*)ctx + (size_t)(b * S_DIM + wq0 + ql) * D_DIM + hh * 64;
#pragma unroll
  for (int db = 0; db < 4; db++)
#pragma unroll
    for (int i = 0; i < 2; i++) {
      unsigned int lo = f2bf(acc[db][2 * i] * inv);
      unsigned int hi = f2bf(acc[db][2 * i + 1] * inv);
      *(unsigned int*)(cp + db * 16 + 4 * g + 2 * i) = lo | (hi << 16);
    }
}

// ---------------- orchestration ----------------------------------------------
extern "C" void kernel_launch(void* const* d_in, const int* in_sizes, int n_in,
                              void* d_out, int out_size, void* d_ws, size_t ws_size,
                              hipStream_t stream) {
  const float* x = (const float*)d_in[0];
  const float* Wq = (const float*)d_in[1];
  const float* Wk = (const float*)d_in[2];
  const float* Wv = (const float*)d_in[3];
  const float* Wo = (const float*)d_in[4];
  const float* bo = (const float*)d_in[5];
  const float* W1 = (const float*)d_in[6];
  const float* b1 = (const float*)d_in[7];
  const float* W2 = (const float*)d_in[8];
  const float* b2 = (const float*)d_in[9];
  const float* ln1s = (const float*)d_in[10];
  const float* ln1b = (const float*)d_in[11];
  const float* ln2s = (const float*)d_in[12];
  const float* ln2b = (const float*)d_in[13];
  float* out = (float*)d_out;

  char* p = (char*)d_ws;
  auto take = [&](size_t n) { char* r = p; p += (n + 255) & ~(size_t)255; return r; };
  __hip_bfloat16* Wqt = (__hip_bfloat16*)take((size_t)1024 * 1024 * 2);
  __hip_bfloat16* Wkt = (__hip_bfloat16*)take((size_t)1024 * 1024 * 2);
  __hip_bfloat16* Wvt = (__hip_bfloat16*)take((size_t)1024 * 1024 * 2);
  __hip_bfloat16* Wot = (__hip_bfloat16*)take((size_t)1024 * 1024 * 2);
  __hip_bfloat16* W1t = (__hip_bfloat16*)take((size_t)4096 * 1024 * 2);
  __hip_bfloat16* W2t = (__hip_bfloat16*)take((size_t)4096 * 1024 * 2);
  // hbuf..vtbuf are contiguous (each 8 MiB, 256B-aligned) and dead by FFN2
  // time -> reused as the 4 split-K bf16 partial buffers.
  __hip_bfloat16* hbuf = (__hip_bfloat16*)take((size_t)NROWS * 1024 * 2);
  __hip_bfloat16* qbuf = (__hip_bfloat16*)take((size_t)NROWS * 1024 * 2);
  __hip_bfloat16* kbuf = (__hip_bfloat16*)take((size_t)NROWS * 1024 * 2);
  __hip_bfloat16* vtbuf = (__hip_bfloat16*)take((size_t)NROWS * 1024 * 2);
  __hip_bfloat16* ctxbuf = (__hip_bfloat16*)take((size_t)NROWS * 1024 * 2);
  float* x1buf = (float*)take((size_t)NROWS * 1024 * 4);
  __hip_bfloat16* h2buf = (__hip_bfloat16*)take((size_t)NROWS * 1024 * 2);
  __hip_bfloat16* gbuf = (__hip_bfloat16*)take((size_t)NROWS * 4096 * 2);
  unsigned short* parts = (unsigned short*)hbuf;

  TcArgs ta;
  ta.src[0] = Wq;  ta.dst[0] = Wqt;  ta.K[0] = 1024; ta.N[0] = 1024; ta.start[0] = 0;
  ta.src[1] = Wk;  ta.dst[1] = Wkt;  ta.K[1] = 1024; ta.N[1] = 1024; ta.start[1] = 1024;
  ta.src[2] = Wv;  ta.dst[2] = Wvt;  ta.K[2] = 1024; ta.N[2] = 1024; ta.start[2] = 2048;
  ta.src[3] = Wo;  ta.dst[3] = Wot;  ta.K[3] = 1024; ta.N[3] = 1024; ta.start[3] = 3072;
  ta.src[4] = W1;  ta.dst[4] = W1t;  ta.K[4] = 1024; ta.N[4] = 4096; ta.start[4] = 4096;
  ta.src[5] = W2;  ta.dst[5] = W2t;  ta.K[5] = 4096; ta.N[5] = 1024; ta.start[5] = 8192;
  transpose_cast6_kernel<<<12288, dim3(32, 8), 0, stream>>>(ta);

  ln_kernel<<<NROWS, 256, 0, stream>>>(x, ln1s, ln1b, hbuf);

  qkv_kernel<<<dim3(32, 24), 256, 0, stream>>>(hbuf, Wqt, Wkt, Wvt, qbuf, kbuf,
                                               (unsigned short*)vtbuf);

  attn_kernel<<<1024, 256, 0, stream>>>(qbuf, kbuf, vtbuf, ctxbuf);

  gemm_bt_kernel<64, 1><<<dim3(32, 16, 1), 256, 0, stream>>>(
      ctxbuf, Wot, x1buf, bo, x, NROWS, 1024, 1024, 1024);

  ln_kernel<<<NROWS, 256, 0, stream>>>(x1buf, ln2s, ln2b, h2buf);

  gemm_bt_kernel<128, 2><<<dim3(32, 32, 1), 256, 0, stream>>>(
      h2buf, W1t, gbuf, b1, nullptr, NROWS, 4096, 1024, 1024);

  gemm_bt_kernel<128, 3><<<dim3(32, 8, 4), 256, 0, stream>>>(
      gbuf, W2t, parts, nullptr, nullptr, NROWS, 1024, 4096, 1024);

  ffn2_reduce_kernel<<<2048, 256, 0, stream>>>(parts, b2, x1buf, out);
}

// Round 5
// 205.799 us; speedup vs baseline: 2.2088x; 1.1930x over previous
//
#include <hip/hip_runtime.h>
#include <hip/hip_bf16.h>
#include <cstdint>

#define D_DIM 1024
#define S_DIM 2048
#define B_DIM 2
#define NROWS 4096
#define H_DIM 16
#define LOG2E 1.4426950408889634f
#define QSCALE (0.125f * LOG2E)

typedef __bf16 bf16x8 __attribute__((ext_vector_type(8)));
typedef float f32x4 __attribute__((ext_vector_type(4)));
typedef unsigned short u16x8 __attribute__((ext_vector_type(8)));

#define MFMA16(a, b, c) __builtin_amdgcn_mfma_f32_16x16x32_bf16(a, b, c, 0, 0, 0)
#define SBAR __builtin_amdgcn_sched_barrier(0)
#define WBAR __builtin_amdgcn_s_barrier()
#define LGKM0 { asm volatile("s_waitcnt lgkmcnt(0)" ::: "memory"); SBAR; }
#define VM6 { asm volatile("s_waitcnt vmcnt(6)" ::: "memory"); SBAR; }
#define VM0 { asm volatile("s_waitcnt vmcnt(0)" ::: "memory"); SBAR; }

__device__ __forceinline__ void async_cp16(const void* g, void* lds) {
  __builtin_amdgcn_global_load_lds(
      (const __attribute__((address_space(1))) void*)(uintptr_t)g,
      (__attribute__((address_space(3))) void*)(uint32_t)(uintptr_t)lds, 16, 0, 0);
}

__device__ __forceinline__ unsigned short f2bf(float f) {
  __hip_bfloat16 h = __float2bfloat16(f);
  return __builtin_bit_cast(unsigned short, h);
}

__device__ __forceinline__ float bf2f(unsigned short u) {
  return __builtin_bit_cast(float, (unsigned int)u << 16);
}

// gelu via sigmoid identity: 0.5*(1+tanh(u)) = 1/(1+exp(-2u)); exp2-space.
__device__ __forceinline__ float gelu_fast(float v) {
  float u = v * v;
  float w = v * fmaf(u, 0.044715f, 1.f);
  float e = exp2f(w * -2.3022161f);  // -2*0.79788456*log2(e)
  return v * __builtin_amdgcn_rcpf(1.f + e);
}

// ---------------- fused weight transpose+cast: 6 matrices in one launch -----
struct TcArgs {
  const float* src[6];
  __hip_bfloat16* dst[6];
  int K[6];
  int N[6];
  int start[6];
};

__global__ __launch_bounds__(256) void transpose_cast6_kernel(TcArgs a) {
  __shared__ float tile[32][33];
  int bid = blockIdx.x, mi = 0;
#pragma unroll
  for (int i = 1; i < 6; i++)
    if (bid >= a.start[i]) mi = i;
  const float* W = a.src[mi];
  __hip_bfloat16* Wt = a.dst[mi];
  int K = a.K[mi], N = a.N[mi];
  int rel = bid - a.start[mi];
  int tilesx = N >> 5;
  int shift = (N == 4096) ? 7 : 5;
  int n0 = (rel & (tilesx - 1)) * 32, k0 = (rel >> shift) * 32;
  int tx = threadIdx.x, ty = threadIdx.y;
#pragma unroll
  for (int i = 0; i < 32; i += 8)
    tile[ty + i][tx] = W[(size_t)(k0 + ty + i) * N + n0 + tx];
  __syncthreads();
#pragma unroll
  for (int i = 0; i < 32; i += 8)
    Wt[(size_t)(n0 + ty + i) * K + k0 + tx] = __float2bfloat16(tile[tx][ty + i]);
}

// ---------------- layernorm (ddof=1) f32 -> bf16 -----------------------------
__global__ __launch_bounds__(256) void ln_kernel(
    const float* __restrict__ x, const float* __restrict__ sc,
    const float* __restrict__ bi, __hip_bfloat16* __restrict__ out) {
  int row = blockIdx.x, t = threadIdx.x;
  float4 v = ((const float4*)(x + (size_t)row * D_DIM))[t];
  float s = v.x + v.y + v.z + v.w;
  float ss = v.x * v.x + v.y * v.y + v.z * v.z + v.w * v.w;
#pragma unroll
  for (int off = 32; off > 0; off >>= 1) {
    s += __shfl_xor(s, off);
    ss += __shfl_xor(ss, off);
  }
  __shared__ float red[8];
  int wid = t >> 6;
  if ((t & 63) == 0) { red[wid] = s; red[4 + wid] = ss; }
  __syncthreads();
  s = red[0] + red[1] + red[2] + red[3];
  ss = red[4] + red[5] + red[6] + red[7];
  float mean = s * (1.f / 1024.f);
  float var = (ss - 1024.f * mean * mean) * (1.f / 1023.f);
  float inv = rsqrtf(var + 1e-5f);
  float4 scv = ((const float4*)sc)[t];
  float4 biv = ((const float4*)bi)[t];
  ushort4 o;
  o.x = f2bf(scv.x * (v.x - mean) * inv + biv.x);
  o.y = f2bf(scv.y * (v.y - mean) * inv + biv.y);
  o.z = f2bf(scv.z * (v.z - mean) * inv + biv.z);
  o.w = f2bf(scv.w * (v.w - mean) * inv + biv.w);
  ((ushort4*)(out + (size_t)row * D_DIM))[t] = o;
}

// ---------------- 256x256 8-phase GEMM, K=1024 (16 K-tiles of 64) ------------
// 8 waves (2M x 4N), per-wave 128x64 out. LDS 128KB: A/B x dbuf x half(128rows)
// x 64 cols bf16, XOR-16B swizzle via inverse-swizzled global source.
// EPI 0: QKV (Q*=QSCALE->qb, K->kb, V transposed -> vt[b,h,d,s], seg by n0>>10)
// EPI 1: gelu(v+bias) -> bf16 C[row*4096+col]
// EPI 2: bf16 partial -> C[z*4096*1024 + row*1024 + col]
template <int EPI>
__global__ __launch_bounds__(512) void gemm256_kernel(
    const __hip_bfloat16* __restrict__ A, const __hip_bfloat16* __restrict__ Bt,
    void* __restrict__ Cout, const float* __restrict__ bias,
    __hip_bfloat16* __restrict__ qb, __hip_bfloat16* __restrict__ kb,
    unsigned short* __restrict__ vt, int strideA, int strideB) {
  __shared__ char lds[131072];
  const int t = threadIdx.x;
  const int lane = t & 63, wid = t >> 6;
  const int ql = lane & 15, g = lane >> 4;
  const int wr = wid >> 2, wc = wid & 3;
  const int m0 = blockIdx.x * 256, n0 = blockIdx.y * 256;
  const int koff = blockIdx.z * 1024;
  const int sw = (ql & 7) << 4;

  // staging constants: thread t covers row (pass*64 + t>>3), 16B chunk t&7.
  const int srow = t >> 3;
  const int scol = ((t & 7) << 4) ^ ((srow & 7) << 4);  // inverse-swizzled src
  const __hip_bfloat16* aBase = A + (size_t)(m0 + srow) * strideA + koff + (scol >> 1);
  const __hip_bfloat16* bBase = Bt + (size_t)(n0 + srow) * strideB + koff + (scol >> 1);
  const uint32_t ldsT = (uint32_t)(t * 16);

  auto stgA = [&](int kt, int half) {
    char* dst = lds + ((kt & 1) * 2 + half) * 16384 + ldsT;
    const __hip_bfloat16* src = aBase + (size_t)(half * 128) * strideA + kt * 64;
    async_cp16(src, dst);
    async_cp16(src + (size_t)64 * strideA, dst + 8192);
  };
  auto stgB = [&](int kt, int half) {
    char* dst = lds + 65536 + ((kt & 1) * 2 + half) * 16384 + ldsT;
    const __hip_bfloat16* src = bBase + (size_t)(half * 128) * strideB + kt * 64;
    async_cp16(src, dst);
    async_cp16(src + (size_t)64 * strideB, dst + 8192);
  };

  bf16x8 aR[4][2], bR[2][2][2];
  f32x4 acc[8][4] = {};

  auto ldA = [&](int slot, int mh) {
    const char* base = lds + (slot * 2 + wr) * 16384;
#pragma unroll
    for (int mi = 0; mi < 4; mi++)
#pragma unroll
      for (int kk = 0; kk < 2; kk++)
        aR[mi][kk] = *(const bf16x8*)(base + (mh * 64 + mi * 16 + ql) * 128 +
                                      ((kk * 64 + g * 16) ^ sw));
  };
  auto ldB = [&](int slot, int nh) {
    const char* base = lds + 65536 + (slot * 2 + (wc >> 1)) * 16384;
#pragma unroll
    for (int ni = 0; ni < 2; ni++)
#pragma unroll
      for (int kk = 0; kk < 2; kk++)
        bR[nh][ni][kk] = *(const bf16x8*)(base + ((wc & 1) * 64 + nh * 32 + ni * 16 + ql) * 128 +
                                          ((kk * 64 + g * 16) ^ sw));
  };
  auto mma = [&](int mh, int nh) {
    __builtin_amdgcn_s_setprio(1);
#pragma unroll
    for (int mi = 0; mi < 4; mi++)
#pragma unroll
      for (int ni = 0; ni < 2; ni++) {
        f32x4 c = acc[mh * 4 + mi][nh * 2 + ni];
        c = MFMA16(aR[mi][0], bR[nh][ni][0], c);
        c = MFMA16(aR[mi][1], bR[nh][ni][1], c);
        acc[mh * 4 + mi][nh * 2 + ni] = c;
      }
    __builtin_amdgcn_s_setprio(0);
  };

  // prologue: kt0 complete + kt1 {B0,B1,A0}; A1(1) arrives in p0 of iter 0.
  stgB(0, 0); stgA(0, 0); stgB(0, 1); stgA(0, 1);
  stgB(1, 0); stgB(1, 1); stgA(1, 0);
  VM6; WBAR;

#pragma unroll 1
  for (int i = 0; i < 7; i++) {
    const int k2 = 2 * i;
    // p0: kt even (slot0) quad(mh0,nh0)
    ldA(0, 0); ldB(0, 0); stgA(k2 + 1, 1); SBAR; WBAR; LGKM0; mma(0, 0); WBAR;
    // p1: quad(mh0,nh1)
    ldB(0, 1); stgB(k2 + 2, 0); SBAR; WBAR; LGKM0; mma(0, 1); WBAR;
    // p2: quad(mh1,nh1)
    ldA(0, 1); stgB(k2 + 2, 1); SBAR; WBAR; LGKM0; mma(1, 1); WBAR;
    // p3: quad(mh1,nh0)
    stgA(k2 + 2, 0); SBAR; WBAR; LGKM0; mma(1, 0); VM6; WBAR;
    // p4: kt odd (slot1) quad(mh0,nh0)
    ldA(1, 0); ldB(1, 0); stgA(k2 + 2, 1); SBAR; WBAR; LGKM0; mma(0, 0); WBAR;
    // p5
    ldB(1, 1); stgB(k2 + 3, 0); SBAR; WBAR; LGKM0; mma(0, 1); WBAR;
    // p6
    ldA(1, 1); stgB(k2 + 3, 1); SBAR; WBAR; LGKM0; mma(1, 1); WBAR;
    // p7
    stgA(k2 + 3, 0); SBAR; WBAR; LGKM0; mma(1, 0); VM6; WBAR;
  }
  // tail: kt14 (slot0), kt15 (slot1); only A1(15) still to stage.
  ldA(0, 0); ldB(0, 0); stgA(15, 1); SBAR; WBAR; LGKM0; mma(0, 0); WBAR;
  ldB(0, 1); SBAR; WBAR; LGKM0; mma(0, 1); WBAR;
  ldA(0, 1); SBAR; WBAR; LGKM0; mma(1, 1); WBAR;
  SBAR; WBAR; LGKM0; mma(1, 0); VM0; WBAR;
  ldA(1, 0); ldB(1, 0); SBAR; WBAR; LGKM0; mma(0, 0); WBAR;
  ldB(1, 1); SBAR; WBAR; LGKM0; mma(0, 1); WBAR;
  ldA(1, 1); SBAR; WBAR; LGKM0; mma(1, 1); WBAR;
  mma(1, 0);

  // ---- epilogue ----
  const int rb = m0 + wr * 128 + (g << 2);
  const int cb = wc * 64 + ql;  // col within 256 tile
  if (EPI == 0) {
    const int seg = n0 >> 10;
    if (seg < 2) {
      __hip_bfloat16* Ob = seg == 0 ? qb : kb;
      const float sc = seg == 0 ? QSCALE : 1.f;
#pragma unroll
      for (int mb = 0; mb < 8; mb++)
#pragma unroll
        for (int nb = 0; nb < 4; nb++) {
          int col = (n0 & 1023) + cb + nb * 16;
#pragma unroll
          for (int rr = 0; rr < 4; rr++)
            Ob[(size_t)(rb + mb * 16 + rr) * 1024 + col] =
                __float2bfloat16(acc[mb][nb][rr] * sc);
        }
    } else {
#pragma unroll
      for (int mb = 0; mb < 8; mb++)
#pragma unroll
        for (int nb = 0; nb < 4; nb++) {
          int csub = (n0 & 1023) + cb + nb * 16;
          int h = csub >> 6, dh = csub & 63;
          int row0 = rb + mb * 16;
          int bb = row0 >> 11, s0 = row0 & 2047;
          ushort4 pk;
          pk.x = f2bf(acc[mb][nb][0]);
          pk.y = f2bf(acc[mb][nb][1]);
          pk.z = f2bf(acc[mb][nb][2]);
          pk.w = f2bf(acc[mb][nb][3]);
          *(ushort4*)(vt + (((size_t)(bb * 16 + h) * 64 + dh) << 11) + s0) = pk;
        }
    }
  } else if (EPI == 1) {
#pragma unroll
    for (int mb = 0; mb < 8; mb++)
#pragma unroll
      for (int nb = 0; nb < 4; nb++) {
        int col = n0 + cb + nb * 16;
        float bv = bias[col];
#pragma unroll
        for (int rr = 0; rr < 4; rr++)
          ((__hip_bfloat16*)Cout)[(size_t)(rb + mb * 16 + rr) * 4096 + col] =
              __float2bfloat16(gelu_fast(acc[mb][nb][rr] + bv));
      }
  } else {
    unsigned short* Cp = (unsigned short*)Cout + (size_t)blockIdx.z * NROWS * 1024;
#pragma unroll
    for (int mb = 0; mb < 8; mb++)
#pragma unroll
      for (int nb = 0; nb < 4; nb++) {
        int col = n0 + cb + nb * 16;
#pragma unroll
        for (int rr = 0; rr < 4; rr++)
          Cp[(size_t)(rb + mb * 16 + rr) * 1024 + col] = f2bf(acc[mb][nb][rr]);
      }
  }
}

// ---------------- old 128x128 2ph GEMM (kept for Wo only) --------------------
template <int BN, int EPI>
__global__ __launch_bounds__(256) void gemm_bt_kernel(
    const __hip_bfloat16* __restrict__ A, const __hip_bfloat16* __restrict__ Bt,
    void* __restrict__ Cout, const float* __restrict__ bias,
    const float* __restrict__ resid, int M, int N, int K, int kchunk) {
  constexpr int NBF = BN / 32;
  __shared__ __hip_bfloat16 As[2][128 * 32];
  __shared__ __hip_bfloat16 Bs[2][BN * 32];
  const int t = threadIdx.x;
  const int lane = t & 63, wid = t >> 6;
  const int ql = lane & 15, g = lane >> 4;
  const int m0 = blockIdx.x * 128, n0 = blockIdx.y * BN;
  const int kz = blockIdx.z;
  const int wm = (wid >> 1) * 64, wn = (wid & 1) * (BN / 2);
  f32x4 acc[4][NBF] = {};
  const int sr = t >> 2, sc8 = (t & 3) * 8;
  const __hip_bfloat16* ag = A + (size_t)(m0 + sr) * K + sc8 + (size_t)kz * kchunk;
  const __hip_bfloat16* bg = Bt + (size_t)(n0 + sr) * K + sc8 + (size_t)kz * kchunk;

  auto stage = [&](int buf, int k0) {
    async_cp16(ag + k0, (char*)&As[buf][0] + wid * 1024);
    async_cp16(ag + (size_t)64 * K + k0, (char*)&As[buf][0] + 4096 + wid * 1024);
    async_cp16(bg + k0, (char*)&Bs[buf][0] + wid * 1024);
    if constexpr (BN == 128)
      async_cp16(bg + (size_t)64 * K + k0, (char*)&Bs[buf][0] + 4096 + wid * 1024);
  };
  auto compute = [&](int buf) {
    bf16x8 af[4], bfr[NBF];
#pragma unroll
    for (int mb = 0; mb < 4; mb++)
      af[mb] = *(const bf16x8*)(&As[buf][(wm + mb * 16 + ql) * 32 + g * 8]);
#pragma unroll
    for (int nb = 0; nb < NBF; nb++)
      bfr[nb] = *(const bf16x8*)(&Bs[buf][(wn + nb * 16 + ql) * 32 + g * 8]);
#pragma unroll
    for (int mb = 0; mb < 4; mb++)
#pragma unroll
      for (int nb = 0; nb < NBF; nb++)
        acc[mb][nb] = MFMA16(af[mb], bfr[nb], acc[mb][nb]);
  };

  stage(0, 0);
  __syncthreads();
  const int nsteps = kchunk >> 5;
  int cur = 0;
  for (int s = 0; s < nsteps - 1; ++s) {
    stage(cur ^ 1, (s + 1) * 32);
    compute(cur);
    __syncthreads();
    cur ^= 1;
  }
  compute(cur);

  const int rb = m0 + wm + (g << 2);
  const int cb = n0 + wn + ql;
#pragma unroll
  for (int mb = 0; mb < 4; mb++) {
#pragma unroll
    for (int nb = 0; nb < NBF; nb++) {
      int col = cb + nb * 16;
#pragma unroll
      for (int r = 0; r < 4; r++) {
        int row = rb + mb * 16 + r;
        float v = acc[mb][nb][r];
        if (EPI == 1) {
          ((float*)Cout)[(size_t)row * N + col] =
              v + bias[col] + resid[(size_t)row * N + col];
        }
      }
    }
  }
}

// ---------------- split-K reduce + bias + residual (f32 out) -----------------
__global__ __launch_bounds__(256) void ffn2_reduce_kernel(
    const unsigned short* __restrict__ parts, const float* __restrict__ bias,
    const float* __restrict__ resid, float* __restrict__ out) {
  const size_t i = ((size_t)blockIdx.x * 256 + threadIdx.x) * 8;
  const int col = (int)(i & 1023);
  float a[8];
  float4 r0 = *(const float4*)(resid + i);
  float4 r1 = *(const float4*)(resid + i + 4);
  float4 b0 = *(const float4*)(bias + col);
  float4 b1 = *(const float4*)(bias + col + 4);
  a[0] = r0.x + b0.x; a[1] = r0.y + b0.y; a[2] = r0.z + b0.z; a[3] = r0.w + b0.w;
  a[4] = r1.x + b1.x; a[5] = r1.y + b1.y; a[6] = r1.z + b1.z; a[7] = r1.w + b1.w;
#pragma unroll
  for (int c = 0; c < 4; c++) {
    u16x8 p = *(const u16x8*)(parts + (size_t)c * ((size_t)NROWS * 1024) + i);
#pragma unroll
    for (int j = 0; j < 8; j++) a[j] += bf2f(p[j]);
  }
  float4 o0 = {a[0], a[1], a[2], a[3]};
  float4 o1 = {a[4], a[5], a[6], a[7]};
  *(float4*)(out + i) = o0;
  *(float4*)(out + i + 4) = o1;
}

// ---------------- causal flash attention, LDS-staged K/V (R4, unchanged) -----
__global__ __launch_bounds__(256) void attn_kernel(
    const __hip_bfloat16* __restrict__ Q, const __hip_bfloat16* __restrict__ Kb,
    const __hip_bfloat16* __restrict__ Vt, __hip_bfloat16* __restrict__ ctx) {
  __shared__ unsigned short Ks[2][64 * 64];
  __shared__ unsigned short Vs[2][64 * 64];
  __shared__ alignas(16) unsigned short Ps[4][16 * 64];
  const int t = threadIdx.x;
  const int lane = t & 63, wid = t >> 6;
  const int ql = lane & 15, g = lane >> 4;
  const int bid = blockIdx.x;
  const int r4 = bid >> 8, k8 = (bid >> 5) & 7, bh = bid & 31;
  const int qt = (r4 == 0) ? 31 - k8 : (r4 == 1) ? 16 + k8 : (r4 == 2) ? 15 - k8 : k8;
  const int b = bh >> 4, hh = bh & 15;
  const int wq0 = qt * 64 + wid * 16;
  const __hip_bfloat16* qp = Q + (size_t)b * S_DIM * D_DIM + hh * 64;
  const __hip_bfloat16* kp = Kb + (size_t)b * S_DIM * D_DIM + hh * 64;
  const __hip_bfloat16* vp = Vt + (size_t)bh * 64 * S_DIM;
  const int kvend = qt * 64 + 64;
  const int swz = (ql & 7) << 4;
  const f32x4 z4 = {0.f, 0.f, 0.f, 0.f};

  auto stageKV = [&](int buf, int kv0) {
    const int sub = lane >> 3, c = lane & 7;
#pragma unroll
    for (int i = 0; i < 2; i++) {
      const int row = wid * 16 + i * 8 + sub;
      const int cs = (c ^ (row & 7)) * 8;
      async_cp16(kp + (size_t)(kv0 + row) * D_DIM + cs,
                 (char*)&Ks[buf][0] + (wid * 16 + i * 8) * 128);
      async_cp16(vp + (size_t)row * S_DIM + kv0 + cs,
                 (char*)&Vs[buf][0] + (wid * 16 + i * 8) * 128);
    }
  };

  bf16x8 qf[2];
#pragma unroll
  for (int hf = 0; hf < 2; hf++)
    qf[hf] = *(const bf16x8*)(qp + (size_t)(wq0 + ql) * D_DIM + hf * 32 + g * 8);

  float m = -3.0e38f, lsum = 0.f;
  f32x4 acc[4] = {};
  unsigned short* Pw = Ps[wid];

  stageKV(0, 0);
  __syncthreads();
  int cur = 0;
  for (int kv0 = 0; kv0 < kvend; kv0 += 64) {
    if (kv0 + 64 < kvend) stageKV(cur ^ 1, kv0 + 64);

    if (kv0 <= wq0 + 15) {
      const char* Kt = (const char*)&Ks[cur][0];
      f32x4 st[4];
#pragma unroll
      for (int ks = 0; ks < 4; ks++) {
        bf16x8 k0 = *(const bf16x8*)(Kt + (ks * 16 + ql) * 128 + ((g * 16) ^ swz));
        bf16x8 k1 = *(const bf16x8*)(Kt + (ks * 16 + ql) * 128 + (((4 + g) * 16) ^ swz));
        st[ks] = MFMA16(k1, qf[1], MFMA16(k0, qf[0], z4));
      }
      if (kv0 + 63 > wq0) {
#pragma unroll
        for (int ks = 0; ks < 4; ks++)
#pragma unroll
          for (int r = 0; r < 4; r++)
            if (kv0 + ks * 16 + 4 * g + r > wq0 + ql) st[ks][r] = -3.0e38f;
      }
      float tm = -3.0e38f;
#pragma unroll
      for (int ks = 0; ks < 4; ks++)
#pragma unroll
        for (int r = 0; r < 4; r++) tm = fmaxf(tm, st[ks][r]);
      tm = fmaxf(tm, __shfl_xor(tm, 16));
      tm = fmaxf(tm, __shfl_xor(tm, 32));
      if (!__all(tm <= m + 8.f)) {
        const float mn = fmaxf(m, tm);
        const float alpha = exp2f(m - mn);
        lsum *= alpha;
#pragma unroll
        for (int db = 0; db < 4; db++) acc[db] *= alpha;
        m = mn;
      }
      float psum = 0.f;
#pragma unroll
      for (int ks = 0; ks < 4; ks++) {
        float p0 = exp2f(st[ks][0] - m), p1 = exp2f(st[ks][1] - m);
        float p2 = exp2f(st[ks][2] - m), p3 = exp2f(st[ks][3] - m);
        psum += (p0 + p1) + (p2 + p3);
        ushort4 pk;
        pk.x = f2bf(p0); pk.y = f2bf(p1); pk.z = f2bf(p2); pk.w = f2bf(p3);
        *(ushort4*)((char*)Pw + ql * 128 + ((ks * 32 + 8 * g) ^ swz)) = pk;
      }
      psum += __shfl_xor(psum, 16);
      psum += __shfl_xor(psum, 32);
      lsum += psum;

      const char* Vtl = (const char*)&Vs[cur][0];
#pragma unroll
      for (int ksl = 0; ksl < 2; ksl++) {
        bf16x8 pb = *(const bf16x8*)((const char*)Pw + ql * 128 + ((ksl * 64 + 16 * g) ^ swz));
#pragma unroll
        for (int db = 0; db < 4; db++) {
          bf16x8 va = *(const bf16x8*)(Vtl + (db * 16 + ql) * 128 + (((ksl * 4 + g) * 16) ^ swz));
          acc[db] = MFMA16(va, pb, acc[db]);
        }
      }
    }
    __syncthreads();
    cur ^= 1;
  }

  const float inv = 1.f / lsum;
  unsigned short* cp = (unsigned short*)ctx + (size_t)(b * S_DIM + wq0 + ql) * D_DIM + hh * 64;
#pragma unroll
  for (int db = 0; db < 4; db++)
#pragma unroll
    for (int i = 0; i < 2; i++) {
      unsigned int lo = f2bf(acc[db][2 * i] * inv);
      unsigned int hi = f2bf(acc[db][2 * i + 1] * inv);
      *(unsigned int*)(cp + db * 16 + 4 * g + 2 * i) = lo | (hi << 16);
    }
}

// ---------------- orchestration ----------------------------------------------
extern "C" void kernel_launch(void* const* d_in, const int* in_sizes, int n_in,
                              void* d_out, int out_size, void* d_ws, size_t ws_size,
                              hipStream_t stream) {
  const float* x = (const float*)d_in[0];
  const float* Wq = (const float*)d_in[1];
  const float* Wk = (const float*)d_in[2];
  const float* Wv = (const float*)d_in[3];
  const float* Wo = (const float*)d_in[4];
  const float* bo = (const float*)d_in[5];
  const float* W1 = (const float*)d_in[6];
  const float* b1 = (const float*)d_in[7];
  const float* W2 = (const float*)d_in[8];
  const float* b2 = (const float*)d_in[9];
  const float* ln1s = (const float*)d_in[10];
  const float* ln1b = (const float*)d_in[11];
  const float* ln2s = (const float*)d_in[12];
  const float* ln2b = (const float*)d_in[13];
  float* out = (float*)d_out;

  char* p = (char*)d_ws;
  auto take = [&](size_t n) { char* r = p; p += (n + 255) & ~(size_t)255; return r; };
  // Wqt/Wkt/Wvt are contiguous -> one [3072][1024] B^T for the fused QKV GEMM.
  __hip_bfloat16* Wqt = (__hip_bfloat16*)take((size_t)1024 * 1024 * 2);
  __hip_bfloat16* Wkt = (__hip_bfloat16*)take((size_t)1024 * 1024 * 2);
  __hip_bfloat16* Wvt = (__hip_bfloat16*)take((size_t)1024 * 1024 * 2);
  __hip_bfloat16* Wot = (__hip_bfloat16*)take((size_t)1024 * 1024 * 2);
  __hip_bfloat16* W1t = (__hip_bfloat16*)take((size_t)4096 * 1024 * 2);
  __hip_bfloat16* W2t = (__hip_bfloat16*)take((size_t)4096 * 1024 * 2);
  __hip_bfloat16* hbuf = (__hip_bfloat16*)take((size_t)NROWS * 1024 * 2);
  __hip_bfloat16* qbuf = (__hip_bfloat16*)take((size_t)NROWS * 1024 * 2);
  __hip_bfloat16* kbuf = (__hip_bfloat16*)take((size_t)NROWS * 1024 * 2);
  __hip_bfloat16* vtbuf = (__hip_bfloat16*)take((size_t)NROWS * 1024 * 2);
  __hip_bfloat16* ctxbuf = (__hip_bfloat16*)take((size_t)NROWS * 1024 * 2);
  float* x1buf = (float*)take((size_t)NROWS * 1024 * 4);
  __hip_bfloat16* h2buf = (__hip_bfloat16*)take((size_t)NROWS * 1024 * 2);
  __hip_bfloat16* gbuf = (__hip_bfloat16*)take((size_t)NROWS * 4096 * 2);
  unsigned short* parts = (unsigned short*)hbuf;

  TcArgs ta;
  ta.src[0] = Wq;  ta.dst[0] = Wqt;  ta.K[0] = 1024; ta.N[0] = 1024; ta.start[0] = 0;
  ta.src[1] = Wk;  ta.dst[1] = Wkt;  ta.K[1] = 1024; ta.N[1] = 1024; ta.start[1] = 1024;
  ta.src[2] = Wv;  ta.dst[2] = Wvt;  ta.K[2] = 1024; ta.N[2] = 1024; ta.start[2] = 2048;
  ta.src[3] = Wo;  ta.dst[3] = Wot;  ta.K[3] = 1024; ta.N[3] = 1024; ta.start[3] = 3072;
  ta.src[4] = W1;  ta.dst[4] = W1t;  ta.K[4] = 1024; ta.N[4] = 4096; ta.start[4] = 4096;
  ta.src[5] = W2;  ta.dst[5] = W2t;  ta.K[5] = 4096; ta.N[5] = 1024; ta.start[5] = 8192;
  transpose_cast6_kernel<<<12288, dim3(32, 8), 0, stream>>>(ta);

  ln_kernel<<<NROWS, 256, 0, stream>>>(x, ln1s, ln1b, hbuf);

  gemm256_kernel<0><<<dim3(16, 12), 512, 0, stream>>>(
      hbuf, Wqt, nullptr, nullptr, qbuf, kbuf, (unsigned short*)vtbuf, 1024, 1024);

  attn_kernel<<<1024, 256, 0, stream>>>(qbuf, kbuf, vtbuf, ctxbuf);

  gemm_bt_kernel<64, 1><<<dim3(32, 16, 1), 256, 0, stream>>>(
      ctxbuf, Wot, x1buf, bo, x, NROWS, 1024, 1024, 1024);

  ln_kernel<<<NROWS, 256, 0, stream>>>(x1buf, ln2s, ln2b, h2buf);

  gemm256_kernel<1><<<dim3(16, 16), 512, 0, stream>>>(
      h2buf, W1t, gbuf, b1, nullptr, nullptr, nullptr, 1024, 1024);

  gemm256_kernel<2><<<dim3(16, 4, 4), 512, 0, stream>>>(
      gbuf, W2t, parts, nullptr, nullptr, nullptr, nullptr, 4096, 4096);

  ffn2_reduce_kernel<<<2048, 256, 0, stream>>>(parts, b2, x1buf, out);
}